// Round 13
// baseline (298.232 us; speedup 1.0000x reference)
//
#include <hip/hip_runtime.h>

#define N_NODES 20000
#define N_EDGES 160000
#define EP (N_EDGES + N_NODES)   // 180000 edges incl. self loops
#define NBLK ((N_NODES + 255) / 256)  // 79
#define PREP_SEG 16384
#define EENC_BLK (N_EDGES / 64)  // 2500 edge-encoder blocks
#define ECLS_BLK (N_EDGES / 64)  // 2500 edge-classifier blocks

typedef __attribute__((ext_vector_type(8))) short bf16x8;
typedef __attribute__((ext_vector_type(4))) float f32x4;

__device__ __forceinline__ short f2bf(float f) {
  unsigned u = __float_as_uint(f);
  unsigned r = (u + 0x7FFFu + ((u >> 16) & 1u)) >> 16;  // RNE
  return (short)r;
}
__device__ __forceinline__ float b2f(short s) {
  return __uint_as_float(((unsigned)(unsigned short)s) << 16);
}

__device__ __forceinline__ f32x4 mfma16(bf16x8 a, bf16x8 b, f32x4 c) {
  return __builtin_amdgcn_mfma_f32_16x16x32_bf16(a, b, c, 0, 0, 0);
}

__device__ __forceinline__ float bcast(float v, int k) {
  return __uint_as_float(__builtin_amdgcn_readlane(__float_as_uint(v), k));
}

__device__ __forceinline__ float wred_sum(float v) {
#pragma unroll
  for (int o = 32; o > 0; o >>= 1) v += __shfl_xor(v, o, 64);
  return v;
}

// async gather: per-lane global src -> linear LDS (base + lane*16)
__device__ __forceinline__ void gl16(const short* g, short* l) {
  __builtin_amdgcn_global_load_lds(
      (const __attribute__((address_space(1))) void*)g,
      (__attribute__((address_space(3))) void*)l, 16, 0, 0);
}

// ---------------- weight fragment prep + cnt/fill zeroing ----------------
__global__ void k_prep_all(const float* __restrict__ cv_wl, const float* __restrict__ cv_wr,
                           const float* __restrict__ cv_we, const float* __restrict__ ec_w1,
                           const float* __restrict__ ee_w2,
                           short* __restrict__ wlf, short* __restrict__ wrf,
                           short* __restrict__ wef, short* __restrict__ updf,
                           short* __restrict__ eclsf, short* __restrict__ encf,
                           int* __restrict__ cnt, int* __restrict__ fill) {
  int i = blockIdx.x * 256 + threadIdx.x;
  if (i < 12 * PREP_SEG) {
    int grp = i / PREP_SEG;
    int r = i % PREP_SEG;
    int kind = grp / 3, l = grp % 3;
    int j = r & 7, lane = (r >> 3) & 63;
    int q = lane & 15, g = lane >> 4;
    if (kind < 3) {  // wl/wr/we : [64,256], out cols c = w*64+t*16+q
      int kh = (r >> 9) & 1, t = (r >> 10) & 3, w = r >> 12;
      int k = kh * 32 + g * 8 + j, c = w * 64 + t * 16 + q;
      const float* W = (kind == 0 ? cv_wl : kind == 1 ? cv_wr : cv_we) + (size_t)l * 64 * 256;
      short* out = (kind == 0 ? wlf : kind == 1 ? wrf : wef) + (size_t)l * PREP_SEG;
      out[r] = f2bf(W[k * 256 + c]);
    } else {        // folded update: Wfold[h*64+kk][c] = 0.25*wl[kk][h*64+c]
      int kh = (r >> 9) & 7, w = r >> 12;
      int k = kh * 32 + g * 8 + j, c = w * 16 + q;
      const float* W = cv_wl + (size_t)l * 64 * 256;
      updf[(size_t)l * PREP_SEG + r] = f2bf(0.25f * W[(k & 63) * 256 + (k >> 6) * 64 + c]);
    }
  } else if (i < 12 * PREP_SEG + 12288) {  // ec_w1 [192,64], 6 k-frags
    int r = i - 12 * PREP_SEG;
    int j = r & 7, lane = (r >> 3) & 63, f = r >> 9;
    int w = f / 6, kh = f % 6;
    int q = lane & 15, g = lane >> 4;
    int k = kh * 32 + g * 8 + j, c = w * 16 + q;
    eclsf[r] = f2bf(ec_w1[(size_t)k * 64 + c]);
  } else if (i < 12 * PREP_SEG + 12288 + 4096) {  // ee_w2 [64,64], 2 k-frags
    int r = i - 12 * PREP_SEG - 12288;
    int j = r & 7, lane = (r >> 3) & 63, f = r >> 9;
    int w = f >> 1, kh = f & 1;
    int q = lane & 15, g = lane >> 4;
    int k = kh * 32 + g * 8 + j, c = w * 16 + q;
    encf[r] = f2bf(ee_w2[(size_t)k * 64 + c]);
  } else {
    int r = i - (12 * PREP_SEG + 12288 + 4096);
    if (r < N_NODES) cnt[r] = 0;
    else if (r < 2 * N_NODES) fill[r - N_NODES] = 0;
  }
}

// ---------------- CSR build ----------------

__global__ void k_count(const int* __restrict__ dst, int* __restrict__ cnt) {
  int i = blockIdx.x * blockDim.x + threadIdx.x;
  if (i < N_EDGES) atomicAdd(&cnt[dst[i]], 1);
}

__global__ void k_scan1(const int* __restrict__ cnt, int* __restrict__ row_ptr,
                        int* __restrict__ bsum) {
  __shared__ int sh[256];
  int t = threadIdx.x, b = blockIdx.x, i = b * 256 + t;
  int v = (i < N_NODES) ? cnt[i] + 1 : 0;  // +1 self loop
  sh[t] = v;
  __syncthreads();
#pragma unroll
  for (int off = 1; off < 256; off <<= 1) {
    int x = (t >= off) ? sh[t - off] : 0;
    __syncthreads();
    sh[t] += x;
    __syncthreads();
  }
  if (i < N_NODES) row_ptr[i + 1] = sh[t];
  if (t == 255) bsum[b] = sh[255];
}

// scan of block sums + offset add fused (one block)
__global__ void k_scan23(const int* __restrict__ bsum, int* __restrict__ row_ptr) {
  __shared__ int sh[256];
  __shared__ int boffs[128];
  int t = threadIdx.x;
  int v = (t < NBLK) ? bsum[t] : 0;
  sh[t] = v;
  __syncthreads();
#pragma unroll
  for (int off = 1; off < 256; off <<= 1) {
    int x = (t >= off) ? sh[t - off] : 0;
    __syncthreads();
    sh[t] += x;
    __syncthreads();
  }
  if (t < NBLK) boffs[t] = sh[t] - v;  // exclusive
  __syncthreads();
  for (int i = t; i < N_NODES; i += 256) row_ptr[i + 1] += boffs[i >> 8];
  if (t == 0) row_ptr[0] = 0;
}

__global__ void k_scatter(const int* __restrict__ dst, const int* __restrict__ row_ptr,
                          int* __restrict__ fill, int* __restrict__ col_idx,
                          int* __restrict__ pdst) {
  int i = blockIdx.x * blockDim.x + threadIdx.x;
  if (i >= EP) return;
  int d = (i < N_EDGES) ? dst[i] : (i - N_EDGES);
  int p = row_ptr[d] + atomicAdd(&fill[d], 1);
  col_idx[p] = i;
  pdst[p] = d;
}

// sort + psrc/pos derivation fused
__global__ void k_sortp(const int* __restrict__ row_ptr, int* __restrict__ col_idx,
                        const int* __restrict__ src, int* __restrict__ psrc,
                        int* __restrict__ pos) {
  int n = blockIdx.x * blockDim.x + threadIdx.x;
  if (n >= N_NODES) return;
  int s = row_ptr[n], e = row_ptr[n + 1];
  for (int i = s + 1; i < e; ++i) {
    int v = col_idx[i];
    int j = i - 1;
    while (j >= s && col_idx[j] > v) { col_idx[j + 1] = col_idx[j]; --j; }
    col_idx[j + 1] = v;
  }
  for (int i = s; i < e; ++i) {
    int eid = col_idx[i];
    pos[eid] = i;
    psrc[i] = (eid < N_EDGES) ? src[eid] : (eid - N_EDGES);
  }
}

// ---------------- fused encoders (edge blocks first, then node blocks) ----------------

__global__ __launch_bounds__(256) void k_enc(
    const float* __restrict__ x,
    const float* __restrict__ nw1, const float* __restrict__ nb1,
    const float* __restrict__ nw2, const float* __restrict__ nb2,
    const float* __restrict__ ea,
    const float* __restrict__ ew1, const float* __restrict__ eb1,
    const short* __restrict__ encf, const float* __restrict__ eb2,
    const int* __restrict__ pos, short* __restrict__ efc,
    float* __restrict__ h, short* __restrict__ hb) {
  __shared__ __align__(16) char smraw[18432];
  int tid = threadIdx.x;
  int lane = tid & 63, w = tid >> 6, q = lane & 15, g = lane >> 4;
  if (blockIdx.x < EENC_BLK) {
    // ---- edge encoder: 64 edges/block ----
    short* hs = (short*)smraw;                 // 64*72 shorts = 9216B
    short* ot = (short*)(smraw + 9216);        // 64*64 shorts = 8192B
    int* ps = (int*)(smraw + 17408);           // 64 ints = 256B
    float* easm = (float*)(smraw + 17664);     // 192 floats = 768B
    int e0 = blockIdx.x * 64;
    if (tid < 64) ps[tid] = pos[e0 + tid];
    if (tid < 192) easm[tid] = ea[(size_t)e0 * 3 + tid];  // coalesced stage
    float w1a = ew1[lane], w1b = ew1[64 + lane], w1c = ew1[128 + lane], b1v = eb1[lane];
    __syncthreads();
#pragma unroll
    for (int t = 0; t < 16; ++t) {
      int e = w * 16 + t;
      float a0 = easm[e * 3], a1 = easm[e * 3 + 1], a2 = easm[e * 3 + 2];  // broadcasts
      float hid = fmaxf(a0 * w1a + a1 * w1b + a2 * w1c + b1v, 0.f);
      hs[e * 72 + lane] = f2bf(hid);
    }
    bf16x8 A0 = *(const bf16x8*)&hs[(w * 16 + q) * 72 + g * 8];
    bf16x8 A1 = *(const bf16x8*)&hs[(w * 16 + q) * 72 + 32 + g * 8];
#pragma unroll
    for (int cc = 0; cc < 4; ++cc) {
      bf16x8 B0 = *(const bf16x8*)(encf + ((size_t)(cc * 2 + 0) * 64 + lane) * 8);
      bf16x8 B1 = *(const bf16x8*)(encf + ((size_t)(cc * 2 + 1) * 64 + lane) * 8);
      f32x4 z = {0.f, 0.f, 0.f, 0.f};
      z = mfma16(A0, B0, z);
      z = mfma16(A1, B1, z);
      float bv = eb2[cc * 16 + q];
#pragma unroll
      for (int r = 0; r < 4; ++r)
        ot[(w * 16 + g * 4 + r) * 64 + cc * 16 + q] = f2bf(z[r] + bv);
    }
    __syncthreads();
    int row = tid >> 2, part = tid & 3;
    short* d = efc + (size_t)ps[row] * 64 + part * 16;
    const short* s = ot + row * 64 + part * 16;
    *(bf16x8*)d = *(const bf16x8*)s;
    *(bf16x8*)(d + 8) = *(const bf16x8*)(s + 8);
  } else {
    // ---- node encoder: 4 nodes/block ----
    float* w2l = (float*)smraw;              // 4096 floats
#pragma unroll
    for (int qq = 0; qq < 16; ++qq) w2l[qq * 256 + tid] = nw2[qq * 256 + tid];
    __syncthreads();
    int n = (blockIdx.x - EENC_BLK) * 4 + w;
    float x0 = x[n * 2], x1 = x[n * 2 + 1];
    float hid = fmaxf(x0 * nw1[lane] + x1 * nw1[64 + lane] + nb1[lane], 0.f);
    float out = nb2[lane];
#pragma unroll
    for (int k = 0; k < 64; ++k) out += bcast(hid, k) * w2l[k * 64 + lane];
    h[n * 64 + lane] = out;
    hb[n * 64 + lane] = f2bf(out);
  }
}

// self-loop row (last CSR slot per node) = mean of node's original-edge rows; 8-row parallel
__global__ __launch_bounds__(256) void k_loop_feat(
    const int* __restrict__ row_ptr, short* __restrict__ efc) {
  int tid = threadIdx.x, lane = tid & 63, w = tid >> 6;
  int n = blockIdx.x * 4 + w;
  int s = row_ptr[n], e1 = row_ptr[n + 1];
  int r8 = lane >> 3, oct = lane & 7;
  float acc[8];
#pragma unroll
  for (int j = 0; j < 8; ++j) acc[j] = 0.f;
  for (int p0 = s; p0 < e1 - 1; p0 += 8) {
    int p = p0 + r8;
    if (p < e1 - 1) {
      bf16x8 A = *(const bf16x8*)(efc + (size_t)p * 64 + oct * 8);
#pragma unroll
      for (int j = 0; j < 8; ++j) acc[j] += b2f(A[j]);
    }
  }
#pragma unroll
  for (int j = 0; j < 8; ++j) {
    acc[j] += __shfl_xor(acc[j], 8, 64);
    acc[j] += __shfl_xor(acc[j], 16, 64);
    acc[j] += __shfl_xor(acc[j], 32, 64);
  }
  int c = e1 - 1 - s;
  float invc = 1.f / (float)(c > 0 ? c : 1);
  if (lane < 8) {
    bf16x8 o8;
#pragma unroll
    for (int j = 0; j < 8; ++j) o8[j] = f2bf(acc[j] * invc);
    *(bf16x8*)(efc + (size_t)(e1 - 1) * 64 + lane * 8) = o8;
  }
}

// ---------------- GAT layer ----------------

// 96 CSR slots/block (6 tiles of 16). r13: stage ONLY hb[src] (true random
// gather, deduped across 4 head-waves) to LDS = 12 KB, 3 gl16/wave; efc
// (pure CSR-order stream) and hb[dst] (CSR-consecutive dup -> L1) loaded
// DIRECT from global in the fully-unrolled compute loop.
__global__ __launch_bounds__(256) void k_elog(
    const short* __restrict__ hb, const short* __restrict__ efc,
    const int* __restrict__ psrc, const int* __restrict__ pdst,
    const short* __restrict__ wlf, const short* __restrict__ wrf,
    const short* __restrict__ wef, const float* __restrict__ bl,
    const float* __restrict__ br, const float* __restrict__ att, float* __restrict__ lg) {
  __shared__ __align__(16) short smA[96 * 64];  // 12 KB (src plane only)
  int tid = threadIdx.x;
  int w = tid >> 6, lane = tid & 63, q = lane & 15, g = lane >> 4;
  int cbase = w * 64;
  int pb = blockIdx.x * 96;

  // ---- staging: 3 x 1KB gather-to-LDS per wave (src rows only) ----
  int id3[3];
#pragma unroll
  for (int j = 0; j < 3; ++j) {
    int s = (w * 3 + j) * 64 + lane;      // 0..767
    int t = s >> 7, s2 = s & 127;
    int e = s2 >> 3;
    id3[j] = psrc[pb + t * 16 + e];
  }
#pragma unroll
  for (int j = 0; j < 3; ++j) {
    int s = (w * 3 + j) * 64 + lane;
    int s2 = s & 127;
    int e = s2 >> 3, c16 = s & 7;
    int cs = (c16 ^ (e & 7)) * 8;         // pre-swizzled short offset
    gl16(hb + (size_t)id3[j] * 64 + cs, &smA[(size_t)s * 8]);
  }

  // dst indices for direct loads
  int nd[6];
#pragma unroll
  for (int t = 0; t < 6; ++t) nd[t] = pdst[pb + t * 16 + q];

  // ---- B fragments (overlap with staging latency) ----
  bf16x8 Bl[4][2], Br[4][2], Be[4][2];
  float av[4], bv[4];
#pragma unroll
  for (int t = 0; t < 4; ++t) {
    int c = cbase + t * 16 + q;
    av[t] = att[c];
    bv[t] = bl[c] + br[c];
#pragma unroll
    for (int kh = 0; kh < 2; ++kh) {
      size_t fo = ((size_t)((w * 4 + t) * 2 + kh) * 64 + lane) * 8;
      Bl[t][kh] = *(const bf16x8*)(wlf + fo);
      Br[t][kh] = *(const bf16x8*)(wrf + fo);
      Be[t][kh] = *(const bf16x8*)(wef + fo);
    }
  }
  __syncthreads();  // drains staging vmcnt; src plane visible

  int xa = (g ^ (q & 7)) * 8;
  int xb = ((4 + g) ^ (q & 7)) * 8;
  int rowoff = q * 64;                    // shorts
#pragma unroll
  for (int t = 0; t < 6; ++t) {
    const short* base = smA + t * 1024;
    const short* ar = hb + (size_t)nd[t] * 64;
    const short* ae = efc + (size_t)(pb + t * 16 + q) * 64;
    bf16x8 As0 = *(const bf16x8*)(base + rowoff + xa);
    bf16x8 As1 = *(const bf16x8*)(base + rowoff + xb);
    bf16x8 Ar0 = *(const bf16x8*)(ar + g * 8);
    bf16x8 Ar1 = *(const bf16x8*)(ar + 32 + g * 8);
    bf16x8 Ae0 = *(const bf16x8*)(ae + g * 8);
    bf16x8 Ae1 = *(const bf16x8*)(ae + 32 + g * 8);
    f32x4 acc[4];
#pragma unroll
    for (int tt = 0; tt < 4; ++tt) {
      f32x4 z = {0.f, 0.f, 0.f, 0.f};
      z = mfma16(As0, Bl[tt][0], z);
      z = mfma16(As1, Bl[tt][1], z);
      z = mfma16(Ar0, Br[tt][0], z);
      z = mfma16(Ar1, Br[tt][1], z);
      z = mfma16(Ae0, Be[tt][0], z);
      acc[tt] = mfma16(Ae1, Be[tt][1], z);
    }
#pragma unroll
    for (int r = 0; r < 4; ++r) {
      float pd = 0.f;
#pragma unroll
      for (int tt = 0; tt < 4; ++tt) {
        float m = acc[tt][r] + bv[tt];
        m = fmaxf(m, 0.2f * m);           // leaky: max(x, 0.2x)
        pd += m * av[tt];
      }
      pd += __shfl_xor(pd, 1, 64);
      pd += __shfl_xor(pd, 2, 64);
      pd += __shfl_xor(pd, 4, 64);
      pd += __shfl_xor(pd, 8, 64);
      if (q == 0) lg[(size_t)(pb + t * 16 + g * 4 + r) * 4 + w] = pd;
    }
  }
}

// fused segment-softmax + aggregation + folded MFMA update.
__global__ __launch_bounds__(256) void k_aggupd(
    const short* __restrict__ hbin, const float* __restrict__ lg,
    const int* __restrict__ row_ptr, const int* __restrict__ psrc,
    const short* __restrict__ updf, const float* __restrict__ bl,
    const float* __restrict__ bias, float* __restrict__ h, short* __restrict__ hbout) {
  __shared__ short agls[16 * 264];      // 264 = 256 + 8 pad
  __shared__ float albuf[4][260];       // per-wave 64-edge x 4-head exp window
  int tid = threadIdx.x, lane = tid & 63, w = tid >> 6;
  int q = lane & 15, g = lane >> 4;
  int n0 = blockIdx.x * 16;
  int i16 = lane & 15, h4 = lane >> 4;  // h4 doubles as 4-wide edge-group id
  float* alw = albuf[w];
#pragma unroll 1
  for (int i = 0; i < 4; ++i) {
    int n = n0 + w * 4 + i;
    int s0 = row_ptr[n], s1 = row_ptr[n + 1];
    // max per head (lane group h4)
    float m = -3.4e38f;
    for (int p = s0 + i16; p < s1; p += 16) m = fmaxf(m, lg[(size_t)p * 4 + h4]);
#pragma unroll
    for (int o = 1; o < 16; o <<= 1) m = fmaxf(m, __shfl_xor(m, o, 64));
    // windowed gather: exp once per (edge,head) -> LDS; partial sum accumulated inline
    float sum = 0.f;
    float acc[4][4];
#pragma unroll
    for (int hh = 0; hh < 4; ++hh)
#pragma unroll
      for (int j = 0; j < 4; ++j) acc[hh][j] = 0.f;
    for (int wst = s0; wst < s1; wst += 64) {
      int wend = wst + 64 < s1 ? wst + 64 : s1;
#pragma unroll
      for (int k = 0; k < 4; ++k) {
        int p = wst + k * 16 + i16;
        float e = (p < s1) ? __expf(lg[(size_t)p * 4 + h4] - m) : 0.f;
        alw[(k * 16 + i16) * 4 + h4] = e;
        sum += e;
      }
      asm volatile("s_waitcnt lgkmcnt(0)" ::: "memory");
      for (int p0 = wst; p0 < wend; p0 += 4) {
        int p = p0 + h4;
        bool v = p < wend;
        int pc = v ? p : wend - 1;
        int sp = psrc[pc];
        float4 al = *(const float4*)&alw[(pc - wst) * 4];
        short4 hv = *(const short4*)(hbin + (size_t)sp * 64 + i16 * 4);
        if (!v) { al.x = 0.f; al.y = 0.f; al.z = 0.f; al.w = 0.f; }
        float hf0 = b2f(hv.x), hf1 = b2f(hv.y), hf2 = b2f(hv.z), hf3 = b2f(hv.w);
        acc[0][0] += al.x * hf0; acc[0][1] += al.x * hf1;
        acc[0][2] += al.x * hf2; acc[0][3] += al.x * hf3;
        acc[1][0] += al.y * hf0; acc[1][1] += al.y * hf1;
        acc[1][2] += al.y * hf2; acc[1][3] += al.y * hf3;
        acc[2][0] += al.z * hf0; acc[2][1] += al.z * hf1;
        acc[2][2] += al.z * hf2; acc[2][3] += al.z * hf3;
        acc[3][0] += al.w * hf0; acc[3][1] += al.w * hf1;
        acc[3][2] += al.w * hf2; acc[3][3] += al.w * hf3;
      }
    }
    // reduce sum over 16 i16-lanes (per head group)
#pragma unroll
    for (int o = 1; o < 16; o <<= 1) sum += __shfl_xor(sum, o, 64);
    float inv = 1.f / sum;
    float ih4[4];
#pragma unroll
    for (int hh = 0; hh < 4; ++hh) ih4[hh] = __shfl(inv, hh * 16, 64);
    // reduce acc over 4 edge-groups (lane>>4): 2 levels
#pragma unroll
    for (int hh = 0; hh < 4; ++hh)
#pragma unroll
      for (int j = 0; j < 4; ++j) {
        acc[hh][j] += __shfl_xor(acc[hh][j], 16, 64);
        acc[hh][j] += __shfl_xor(acc[hh][j], 32, 64);
      }
    if (lane < 16) {
#pragma unroll
      for (int hh = 0; hh < 4; ++hh) {
        short4 o4;
        o4.x = f2bf(acc[hh][0] * ih4[hh]);
        o4.y = f2bf(acc[hh][1] * ih4[hh]);
        o4.z = f2bf(acc[hh][2] * ih4[hh]);
        o4.w = f2bf(acc[hh][3] * ih4[hh]);
        *(short4*)(agls + (w * 4 + i) * 264 + hh * 64 + i16 * 4) = o4;
      }
    }
  }
  __syncthreads();
  // MFMA update: A row = node q (agg, K=256), B = folded weights; out cols w*16..+16
  const short* arow = agls + q * 264;
  f32x4 z = {0.f, 0.f, 0.f, 0.f};
#pragma unroll
  for (int kh = 0; kh < 8; ++kh) {
    bf16x8 A = *(const bf16x8*)(arow + kh * 32 + g * 8);
    bf16x8 B = *(const bf16x8*)(updf + ((size_t)(w * 8 + kh) * 64 + lane) * 8);
    z = mfma16(A, B, z);
  }
  int c = w * 16 + q;
  float bf = 0.25f * (bl[c] + bl[64 + c] + bl[128 + c] + bl[192 + c]) + bias[c];
#pragma unroll
  for (int r = 0; r < 4; ++r) {
    int n = n0 + g * 4 + r;
    float nh = h[(size_t)n * 64 + c] + fmaxf(z[r] + bf, 0.f);
    h[(size_t)n * 64 + c] = nh;
    hbout[(size_t)n * 64 + c] = f2bf(nh);
  }
}

// ---------------- fused output heads ----------------
__global__ __launch_bounds__(256) void k_heads(
    const short* __restrict__ hb, const short* __restrict__ efc,
    const int* __restrict__ src, const int* __restrict__ dst,
    const int* __restrict__ pos, const short* __restrict__ eclsf,
    const float* __restrict__ b1, const float* __restrict__ w2,
    const float* __restrict__ b2,
    const float* __restrict__ h, const float* __restrict__ ow1,
    const float* __restrict__ ob1, const float* __restrict__ ow2,
    const float* __restrict__ ob2, float* __restrict__ out) {
  __shared__ __align__(16) char smraw[25600];
  int tid = threadIdx.x;
  int w = tid >> 6, lane = tid & 63, q = lane & 15, g = lane >> 4;
  if (blockIdx.x < ECLS_BLK) {
    short* smA = (short*)smraw;                  // 3 planes x 64 edges x 64 shorts = 24 KB
    float* sm = (float*)(smraw + 24576);         // 256 floats
    int e0b = blockIdx.x * 64;
    int id6[6];
#pragma unroll
    for (int j = 0; j < 6; ++j) {
      int s = (w * 6 + j) * 64 + lane;           // 0..1535
      int r = s >> 9, e = (s >> 3) & 63;
      int eg = e0b + e;
      id6[j] = (r == 0) ? src[eg] : (r == 1) ? dst[eg] : pos[eg];
    }
#pragma unroll
    for (int j = 0; j < 6; ++j) {
      int s = (w * 6 + j) * 64 + lane;
      int r = s >> 9, e = (s >> 3) & 63, c16 = s & 7;
      int cs = (c16 ^ (e & 7)) * 8;              // pre-swizzled short offset
      const short* gp = ((r == 2) ? efc : hb) + (size_t)id6[j] * 64 + cs;
      gl16(gp, &smA[(size_t)s * 8]);
    }
    int c = w * 16 + q;
    bf16x8 Bf[6];
#pragma unroll
    for (int kh = 0; kh < 6; ++kh)
      Bf[kh] = *(const bf16x8*)(eclsf + ((size_t)(w * 6 + kh) * 64 + lane) * 8);
    float b1v = b1[c], w2v = w2[c], b2v = b2[0];
    __syncthreads();  // drains staging vmcnt
    int xa = (g ^ (q & 7)) * 8;
    int xb = ((4 + g) ^ (q & 7)) * 8;
#pragma unroll
    for (int tile = 0; tile < 4; ++tile) {
      const short* rp = smA + (tile * 16 + q) * 64;
      f32x4 acc = {0.f, 0.f, 0.f, 0.f};
      acc = mfma16(*(const bf16x8*)(rp + xa), Bf[0], acc);
      acc = mfma16(*(const bf16x8*)(rp + xb), Bf[1], acc);
      acc = mfma16(*(const bf16x8*)(rp + 4096 + xa), Bf[2], acc);
      acc = mfma16(*(const bf16x8*)(rp + 4096 + xb), Bf[3], acc);
      acc = mfma16(*(const bf16x8*)(rp + 8192 + xa), Bf[4], acc);
      acc = mfma16(*(const bf16x8*)(rp + 8192 + xb), Bf[5], acc);
#pragma unroll
      for (int r = 0; r < 4; ++r) {
        float hv = fmaxf(acc[r] + b1v, 0.f) * w2v;
        hv += __shfl_xor(hv, 1, 64);
        hv += __shfl_xor(hv, 2, 64);
        hv += __shfl_xor(hv, 4, 64);
        hv += __shfl_xor(hv, 8, 64);
        if (q == 0) sm[tile * 64 + w * 16 + g * 4 + r] = hv;
      }
    }
    __syncthreads();
    if (tid < 64) {
      int tile = tid >> 4, e = tid & 15;
      float t = sm[tile * 64 + e] + sm[tile * 64 + 16 + e] +
                sm[tile * 64 + 32 + e] + sm[tile * 64 + 48 + e] + b2v;
      out[e0b + tile * 16 + e] = 1.f / (1.f + __expf(-t));
    }
  } else {
    // ---- offset regressor ----
    float* w1l = (float*)smraw;  // 4096 floats
#pragma unroll
    for (int qq = 0; qq < 16; ++qq) w1l[qq * 256 + tid] = ow1[qq * 256 + tid];
    __syncthreads();
    int n = (blockIdx.x - ECLS_BLK) * 4 + w;
    float hr = h[n * 64 + lane];
    float hid = ob1[lane];
#pragma unroll
    for (int k = 0; k < 64; ++k) hid += bcast(hr, k) * w1l[k * 64 + lane];
    hid = fmaxf(hid, 0.f);
    float p0 = wred_sum(hid * ow2[lane * 2]);
    float p1 = wred_sum(hid * ow2[lane * 2 + 1]);
    if (lane == 0) {
      out[N_EDGES + n * 2] = p0 + ob2[0];
      out[N_EDGES + n * 2 + 1] = p1 + ob2[1];
    }
  }
}

// ---------------- launcher ----------------

extern "C" void kernel_launch(void* const* d_in, const int* in_sizes, int n_in,
                              void* d_out, int out_size, void* d_ws, size_t ws_size,
                              hipStream_t stream) {
  const float* x     = (const float*)d_in[0];
  const int*   eidx  = (const int*)d_in[1];
  const float* eattr = (const float*)d_in[2];
  const float* ne_w1 = (const float*)d_in[3];
  const float* ne_b1 = (const float*)d_in[4];
  const float* ne_w2 = (const float*)d_in[5];
  const float* ne_b2 = (const float*)d_in[6];
  const float* ee_w1 = (const float*)d_in[7];
  const float* ee_b1 = (const float*)d_in[8];
  const float* ee_w2 = (const float*)d_in[9];
  const float* ee_b2 = (const float*)d_in[10];
  const float* cv_wl = (const float*)d_in[11];
  const float* cv_bl = (const float*)d_in[12];
  const float* cv_wr = (const float*)d_in[13];
  const float* cv_br = (const float*)d_in[14];
  const float* cv_we = (const float*)d_in[15];
  const float* cv_att = (const float*)d_in[16];
  const float* cv_bias = (const float*)d_in[17];
  const float* ec_w1 = (const float*)d_in[18];
  const float* ec_b1 = (const float*)d_in[19];
  const float* ec_w2 = (const float*)d_in[20];
  const float* ec_b2 = (const float*)d_in[21];
  const float* or_w1 = (const float*)d_in[22];
  const float* or_b1 = (const float*)d_in[23];
  const float* or_w2 = (const float*)d_in[24];
  const float* or_b2 = (const float*)d_in[25];

  const int* src = eidx;
  const int* dst = eidx + N_EDGES;

  // workspace layout
  float* fws = (float*)d_ws;
  size_t o = 0;
  float* h  = fws + o; o += (size_t)N_NODES * 64;
  float* lg = fws + o; o += (size_t)EP * 4;   // layout [p][4]
  short* sws = (short*)(fws + o);
  size_t so = 0;
  short* hb0  = sws + so; so += (size_t)N_NODES * 64;
  short* hb1  = sws + so; so += (size_t)N_NODES * 64;
  short* efc  = sws + so; so += (size_t)EP * 64;
  short* wlf  = sws + so; so += 3 * PREP_SEG;
  short* wrf  = sws + so; so += 3 * PREP_SEG;
  short* wef  = sws + so; so += 3 * PREP_SEG;
  short* updf = sws + so; so += 3 * PREP_SEG;
  short* eclsf = sws + so; so += 12288;
  short* encf  = sws + so; so += 4096;
  int* iws = (int*)(sws + so + (so & 1));
  int* row_ptr = iws;
  int* col_idx = iws + (N_NODES + 64);
  int* pdst = col_idx + EP;
  int* psrc = pdst + EP;
  int* pos  = psrc + EP;
  int* cnt  = pos + EP;
  int* fill = cnt + N_NODES;
  int* bsum = fill + N_NODES;

  float* out = (float*)d_out;

  // weight fragment prep + cnt/fill zeroing
  k_prep_all<<<(12 * PREP_SEG + 12288 + 4096 + 2 * N_NODES + 255) / 256, 256, 0, stream>>>(
      cv_wl, cv_wr, cv_we, ec_w1, ee_w2, wlf, wrf, wef, updf, eclsf, encf, cnt, fill);

  // CSR build
  k_count<<<(N_EDGES + 255) / 256, 256, 0, stream>>>(dst, cnt);
  k_scan1<<<NBLK, 256, 0, stream>>>(cnt, row_ptr, bsum);
  k_scan23<<<1, 256, 0, stream>>>(bsum, row_ptr);
  k_scatter<<<(EP + 255) / 256, 256, 0, stream>>>(dst, row_ptr, fill, col_idx, pdst);
  k_sortp<<<(N_NODES + 255) / 256, 256, 0, stream>>>(row_ptr, col_idx, src, psrc, pos);

  // encoders (edge blocks + node blocks fused)
  k_enc<<<EENC_BLK + N_NODES / 4, 256, 0, stream>>>(
      x, ne_w1, ne_b1, ne_w2, ne_b2, eattr, ee_w1, ee_b1, encf, ee_b2, pos, efc, h, hb0);
  k_loop_feat<<<N_NODES / 4, 256, 0, stream>>>(row_ptr, efc);

  // 3 GATv2 layers (hb ping-pong)
  short* hcur = hb0;
  short* hnxt = hb1;
  for (int l = 0; l < 3; ++l) {
    const float* bl = cv_bl + (size_t)l * 256;
    const float* br = cv_br + (size_t)l * 256;
    const float* at = cv_att + (size_t)l * 256;
    const float* bi = cv_bias + (size_t)l * 64;
    k_elog<<<EP / 96, 256, 0, stream>>>(hcur, efc, psrc, pdst,
                                        wlf + (size_t)l * PREP_SEG,
                                        wrf + (size_t)l * PREP_SEG,
                                        wef + (size_t)l * PREP_SEG, bl, br, at, lg);
    k_aggupd<<<N_NODES / 16, 256, 0, stream>>>(hcur, lg, row_ptr, psrc,
                                               updf + (size_t)l * PREP_SEG, bl, bi, h, hnxt);
    short* tmp = hcur; hcur = hnxt; hnxt = tmp;
  }

  // fused heads (final hb = hcur)
  k_heads<<<ECLS_BLK + N_NODES / 4, 256, 0, stream>>>(
      hcur, efc, src, dst, pos, eclsf, ec_b1, ec_w2, ec_b2,
      h, or_w1, or_b1, or_w2, or_b2, out);
}

// Round 14
// 283.775 us; speedup vs baseline: 1.0509x; 1.0509x over previous
//
#include <hip/hip_runtime.h>

#define N_NODES 20000
#define N_EDGES 160000
#define EP (N_EDGES + N_NODES)   // 180000 edges incl. self loops
#define NBLK ((N_NODES + 255) / 256)  // 79
#define PREP_SEG 16384
#define EENC_BLK (N_EDGES / 64)  // 2500 edge-encoder blocks
#define ECLS_BLK (N_EDGES / 64)  // 2500 edge-classifier blocks

typedef __attribute__((ext_vector_type(8))) short bf16x8;
typedef __attribute__((ext_vector_type(4))) float f32x4;

__device__ __forceinline__ short f2bf(float f) {
  unsigned u = __float_as_uint(f);
  unsigned r = (u + 0x7FFFu + ((u >> 16) & 1u)) >> 16;  // RNE
  return (short)r;
}
__device__ __forceinline__ float b2f(short s) {
  return __uint_as_float(((unsigned)(unsigned short)s) << 16);
}

__device__ __forceinline__ f32x4 mfma16(bf16x8 a, bf16x8 b, f32x4 c) {
  return __builtin_amdgcn_mfma_f32_16x16x32_bf16(a, b, c, 0, 0, 0);
}

__device__ __forceinline__ float bcast(float v, int k) {
  return __uint_as_float(__builtin_amdgcn_readlane(__float_as_uint(v), k));
}

__device__ __forceinline__ float wred_sum(float v) {
#pragma unroll
  for (int o = 32; o > 0; o >>= 1) v += __shfl_xor(v, o, 64);
  return v;
}

// async gather: per-lane global src -> linear LDS (base + lane*16)
__device__ __forceinline__ void gl16(const short* g, short* l) {
  __builtin_amdgcn_global_load_lds(
      (const __attribute__((address_space(1))) void*)g,
      (__attribute__((address_space(3))) void*)l, 16, 0, 0);
}

// ---------------- weight fragment prep + cnt/fill zeroing ----------------
__global__ void k_prep_all(const float* __restrict__ cv_wl, const float* __restrict__ cv_wr,
                           const float* __restrict__ cv_we, const float* __restrict__ ec_w1,
                           const float* __restrict__ ee_w2,
                           short* __restrict__ wlf, short* __restrict__ wrf,
                           short* __restrict__ wef, short* __restrict__ updf,
                           short* __restrict__ eclsf, short* __restrict__ encf,
                           int* __restrict__ cnt, int* __restrict__ fill) {
  int i = blockIdx.x * 256 + threadIdx.x;
  if (i < 12 * PREP_SEG) {
    int grp = i / PREP_SEG;
    int r = i % PREP_SEG;
    int kind = grp / 3, l = grp % 3;
    int j = r & 7, lane = (r >> 3) & 63;
    int q = lane & 15, g = lane >> 4;
    if (kind < 3) {  // wl/wr/we : [64,256], out cols c = w*64+t*16+q
      int kh = (r >> 9) & 1, t = (r >> 10) & 3, w = r >> 12;
      int k = kh * 32 + g * 8 + j, c = w * 64 + t * 16 + q;
      const float* W = (kind == 0 ? cv_wl : kind == 1 ? cv_wr : cv_we) + (size_t)l * 64 * 256;
      short* out = (kind == 0 ? wlf : kind == 1 ? wrf : wef) + (size_t)l * PREP_SEG;
      out[r] = f2bf(W[k * 256 + c]);
    } else {        // folded update: Wfold[h*64+kk][c] = 0.25*wl[kk][h*64+c]
      int kh = (r >> 9) & 7, w = r >> 12;
      int k = kh * 32 + g * 8 + j, c = w * 16 + q;
      const float* W = cv_wl + (size_t)l * 64 * 256;
      updf[(size_t)l * PREP_SEG + r] = f2bf(0.25f * W[(k & 63) * 256 + (k >> 6) * 64 + c]);
    }
  } else if (i < 12 * PREP_SEG + 12288) {  // ec_w1 [192,64], 6 k-frags
    int r = i - 12 * PREP_SEG;
    int j = r & 7, lane = (r >> 3) & 63, f = r >> 9;
    int w = f / 6, kh = f % 6;
    int q = lane & 15, g = lane >> 4;
    int k = kh * 32 + g * 8 + j, c = w * 16 + q;
    eclsf[r] = f2bf(ec_w1[(size_t)k * 64 + c]);
  } else if (i < 12 * PREP_SEG + 12288 + 4096) {  // ee_w2 [64,64], 2 k-frags
    int r = i - 12 * PREP_SEG - 12288;
    int j = r & 7, lane = (r >> 3) & 63, f = r >> 9;
    int w = f >> 1, kh = f & 1;
    int q = lane & 15, g = lane >> 4;
    int k = kh * 32 + g * 8 + j, c = w * 16 + q;
    encf[r] = f2bf(ee_w2[(size_t)k * 64 + c]);
  } else {
    int r = i - (12 * PREP_SEG + 12288 + 4096);
    if (r < N_NODES) cnt[r] = 0;
    else if (r < 2 * N_NODES) fill[r - N_NODES] = 0;
  }
}

// ---------------- CSR build ----------------

__global__ void k_count(const int* __restrict__ dst, int* __restrict__ cnt) {
  int i = blockIdx.x * blockDim.x + threadIdx.x;
  if (i < N_EDGES) atomicAdd(&cnt[dst[i]], 1);
}

__global__ void k_scan1(const int* __restrict__ cnt, int* __restrict__ row_ptr,
                        int* __restrict__ bsum) {
  __shared__ int sh[256];
  int t = threadIdx.x, b = blockIdx.x, i = b * 256 + t;
  int v = (i < N_NODES) ? cnt[i] + 1 : 0;  // +1 self loop
  sh[t] = v;
  __syncthreads();
#pragma unroll
  for (int off = 1; off < 256; off <<= 1) {
    int x = (t >= off) ? sh[t - off] : 0;
    __syncthreads();
    sh[t] += x;
    __syncthreads();
  }
  if (i < N_NODES) row_ptr[i + 1] = sh[t];
  if (t == 255) bsum[b] = sh[255];
}

// scan of block sums + offset add fused (one block)
__global__ void k_scan23(const int* __restrict__ bsum, int* __restrict__ row_ptr) {
  __shared__ int sh[256];
  __shared__ int boffs[128];
  int t = threadIdx.x;
  int v = (t < NBLK) ? bsum[t] : 0;
  sh[t] = v;
  __syncthreads();
#pragma unroll
  for (int off = 1; off < 256; off <<= 1) {
    int x = (t >= off) ? sh[t - off] : 0;
    __syncthreads();
    sh[t] += x;
    __syncthreads();
  }
  if (t < NBLK) boffs[t] = sh[t] - v;  // exclusive
  __syncthreads();
  for (int i = t; i < N_NODES; i += 256) row_ptr[i + 1] += boffs[i >> 8];
  if (t == 0) row_ptr[0] = 0;
}

__global__ void k_scatter(const int* __restrict__ dst, const int* __restrict__ row_ptr,
                          int* __restrict__ fill, int* __restrict__ col_idx,
                          int* __restrict__ pdst) {
  int i = blockIdx.x * blockDim.x + threadIdx.x;
  if (i >= EP) return;
  int d = (i < N_EDGES) ? dst[i] : (i - N_EDGES);
  int p = row_ptr[d] + atomicAdd(&fill[d], 1);
  col_idx[p] = i;
  pdst[p] = d;
}

// sort + psrc/pos derivation fused
__global__ void k_sortp(const int* __restrict__ row_ptr, int* __restrict__ col_idx,
                        const int* __restrict__ src, int* __restrict__ psrc,
                        int* __restrict__ pos) {
  int n = blockIdx.x * blockDim.x + threadIdx.x;
  if (n >= N_NODES) return;
  int s = row_ptr[n], e = row_ptr[n + 1];
  for (int i = s + 1; i < e; ++i) {
    int v = col_idx[i];
    int j = i - 1;
    while (j >= s && col_idx[j] > v) { col_idx[j + 1] = col_idx[j]; --j; }
    col_idx[j + 1] = v;
  }
  for (int i = s; i < e; ++i) {
    int eid = col_idx[i];
    pos[eid] = i;
    psrc[i] = (eid < N_EDGES) ? src[eid] : (eid - N_EDGES);
  }
}

// ---------------- fused encoders (edge blocks first, then node blocks) ----------------

__global__ __launch_bounds__(256) void k_enc(
    const float* __restrict__ x,
    const float* __restrict__ nw1, const float* __restrict__ nb1,
    const float* __restrict__ nw2, const float* __restrict__ nb2,
    const float* __restrict__ ea,
    const float* __restrict__ ew1, const float* __restrict__ eb1,
    const short* __restrict__ encf, const float* __restrict__ eb2,
    const int* __restrict__ pos, short* __restrict__ efc,
    float* __restrict__ h, short* __restrict__ hb) {
  __shared__ __align__(16) char smraw[18432];
  int tid = threadIdx.x;
  int lane = tid & 63, w = tid >> 6, q = lane & 15, g = lane >> 4;
  if (blockIdx.x < EENC_BLK) {
    // ---- edge encoder: 64 edges/block ----
    short* hs = (short*)smraw;                 // 64*72 shorts = 9216B
    short* ot = (short*)(smraw + 9216);        // 64*64 shorts = 8192B
    int* ps = (int*)(smraw + 17408);           // 64 ints = 256B
    float* easm = (float*)(smraw + 17664);     // 192 floats = 768B
    int e0 = blockIdx.x * 64;
    if (tid < 64) ps[tid] = pos[e0 + tid];
    if (tid < 192) easm[tid] = ea[(size_t)e0 * 3 + tid];  // coalesced stage
    float w1a = ew1[lane], w1b = ew1[64 + lane], w1c = ew1[128 + lane], b1v = eb1[lane];
    __syncthreads();
#pragma unroll
    for (int t = 0; t < 16; ++t) {
      int e = w * 16 + t;
      float a0 = easm[e * 3], a1 = easm[e * 3 + 1], a2 = easm[e * 3 + 2];  // broadcasts
      float hid = fmaxf(a0 * w1a + a1 * w1b + a2 * w1c + b1v, 0.f);
      hs[e * 72 + lane] = f2bf(hid);
    }
    bf16x8 A0 = *(const bf16x8*)&hs[(w * 16 + q) * 72 + g * 8];
    bf16x8 A1 = *(const bf16x8*)&hs[(w * 16 + q) * 72 + 32 + g * 8];
#pragma unroll
    for (int cc = 0; cc < 4; ++cc) {
      bf16x8 B0 = *(const bf16x8*)(encf + ((size_t)(cc * 2 + 0) * 64 + lane) * 8);
      bf16x8 B1 = *(const bf16x8*)(encf + ((size_t)(cc * 2 + 1) * 64 + lane) * 8);
      f32x4 z = {0.f, 0.f, 0.f, 0.f};
      z = mfma16(A0, B0, z);
      z = mfma16(A1, B1, z);
      float bv = eb2[cc * 16 + q];
#pragma unroll
      for (int r = 0; r < 4; ++r)
        ot[(w * 16 + g * 4 + r) * 64 + cc * 16 + q] = f2bf(z[r] + bv);
    }
    __syncthreads();
    int row = tid >> 2, part = tid & 3;
    short* d = efc + (size_t)ps[row] * 64 + part * 16;
    const short* s = ot + row * 64 + part * 16;
    *(bf16x8*)d = *(const bf16x8*)s;
    *(bf16x8*)(d + 8) = *(const bf16x8*)(s + 8);
  } else {
    // ---- node encoder: 4 nodes/block ----
    float* w2l = (float*)smraw;              // 4096 floats
#pragma unroll
    for (int qq = 0; qq < 16; ++qq) w2l[qq * 256 + tid] = nw2[qq * 256 + tid];
    __syncthreads();
    int n = (blockIdx.x - EENC_BLK) * 4 + w;
    float x0 = x[n * 2], x1 = x[n * 2 + 1];
    float hid = fmaxf(x0 * nw1[lane] + x1 * nw1[64 + lane] + nb1[lane], 0.f);
    float out = nb2[lane];
#pragma unroll
    for (int k = 0; k < 64; ++k) out += bcast(hid, k) * w2l[k * 64 + lane];
    h[n * 64 + lane] = out;
    hb[n * 64 + lane] = f2bf(out);
  }
}

// self-loop row (last CSR slot per node) = mean of node's original-edge rows; 8-row parallel
__global__ __launch_bounds__(256) void k_loop_feat(
    const int* __restrict__ row_ptr, short* __restrict__ efc) {
  int tid = threadIdx.x, lane = tid & 63, w = tid >> 6;
  int n = blockIdx.x * 4 + w;
  int s = row_ptr[n], e1 = row_ptr[n + 1];
  int r8 = lane >> 3, oct = lane & 7;
  float acc[8];
#pragma unroll
  for (int j = 0; j < 8; ++j) acc[j] = 0.f;
  for (int p0 = s; p0 < e1 - 1; p0 += 8) {
    int p = p0 + r8;
    if (p < e1 - 1) {
      bf16x8 A = *(const bf16x8*)(efc + (size_t)p * 64 + oct * 8);
#pragma unroll
      for (int j = 0; j < 8; ++j) acc[j] += b2f(A[j]);
    }
  }
#pragma unroll
  for (int j = 0; j < 8; ++j) {
    acc[j] += __shfl_xor(acc[j], 8, 64);
    acc[j] += __shfl_xor(acc[j], 16, 64);
    acc[j] += __shfl_xor(acc[j], 32, 64);
  }
  int c = e1 - 1 - s;
  float invc = 1.f / (float)(c > 0 ? c : 1);
  if (lane < 8) {
    bf16x8 o8;
#pragma unroll
    for (int j = 0; j < 8; ++j) o8[j] = f2bf(acc[j] * invc);
    *(bf16x8*)(efc + (size_t)(e1 - 1) * 64 + lane * 8) = o8;
  }
}

// ---------------- GAT layer ----------------

// 96 CSR slots/block (6 tiles of 16). Stage {hb[src], efc} to LDS (24 KB);
// hb[dst] direct from global (CSR-consecutive dup -> L1); single barrier;
// full-unroll compute. (r12 configuration — best known good.)
__global__ __launch_bounds__(256) void k_elog(
    const short* __restrict__ hb, const short* __restrict__ efc,
    const int* __restrict__ psrc, const int* __restrict__ pdst,
    const short* __restrict__ wlf, const short* __restrict__ wrf,
    const short* __restrict__ wef, const float* __restrict__ bl,
    const float* __restrict__ br, const float* __restrict__ att, float* __restrict__ lg) {
  __shared__ __align__(16) short smA[96 * 2 * 64];  // 24 KB
  int tid = threadIdx.x;
  int w = tid >> 6, lane = tid & 63, q = lane & 15, g = lane >> 4;
  int cbase = w * 64;
  int pb = blockIdx.x * 96;

  int id6[6];
#pragma unroll
  for (int j = 0; j < 6; ++j) {
    int s = (w * 6 + j) * 64 + lane;      // 0..1535
    int t = s >> 8, s2 = s & 255;
    int r = s2 >> 7, e = (s2 >> 3) & 15;
    int pe = pb + t * 16 + e;
    id6[j] = (r == 0) ? psrc[pe] : pe;
  }
#pragma unroll
  for (int j = 0; j < 6; ++j) {
    int s = (w * 6 + j) * 64 + lane;
    int s2 = s & 255;
    int r = s2 >> 7, e = (s2 >> 3) & 15, c16 = s & 7;
    int cs = (c16 ^ (e & 7)) * 8;         // pre-swizzled short offset
    const short* gp = ((r == 1) ? efc : hb) + (size_t)id6[j] * 64 + cs;
    gl16(gp, &smA[(size_t)s * 8]);
  }

  int nd[6];
#pragma unroll
  for (int t = 0; t < 6; ++t) nd[t] = pdst[pb + t * 16 + q];

  bf16x8 Bl[4][2], Br[4][2], Be[4][2];
  float av[4], bv[4];
#pragma unroll
  for (int t = 0; t < 4; ++t) {
    int c = cbase + t * 16 + q;
    av[t] = att[c];
    bv[t] = bl[c] + br[c];
#pragma unroll
    for (int kh = 0; kh < 2; ++kh) {
      size_t fo = ((size_t)((w * 4 + t) * 2 + kh) * 64 + lane) * 8;
      Bl[t][kh] = *(const bf16x8*)(wlf + fo);
      Br[t][kh] = *(const bf16x8*)(wrf + fo);
      Be[t][kh] = *(const bf16x8*)(wef + fo);
    }
  }
  __syncthreads();  // drains staging vmcnt; all tiles visible

  int xa = (g ^ (q & 7)) * 8;
  int xb = ((4 + g) ^ (q & 7)) * 8;
  int rowoff = q * 64;                    // shorts
#pragma unroll
  for (int t = 0; t < 6; ++t) {
    const short* base = smA + t * 2048;
    const short* ar = hb + (size_t)nd[t] * 64;
    bf16x8 As0 = *(const bf16x8*)(base + rowoff + xa);
    bf16x8 As1 = *(const bf16x8*)(base + rowoff + xb);
    bf16x8 Ar0 = *(const bf16x8*)(ar + g * 8);
    bf16x8 Ar1 = *(const bf16x8*)(ar + 32 + g * 8);
    bf16x8 Ae0 = *(const bf16x8*)(base + 1024 + rowoff + xa);
    bf16x8 Ae1 = *(const bf16x8*)(base + 1024 + rowoff + xb);
    f32x4 acc[4];
#pragma unroll
    for (int tt = 0; tt < 4; ++tt) {
      f32x4 z = {0.f, 0.f, 0.f, 0.f};
      z = mfma16(As0, Bl[tt][0], z);
      z = mfma16(As1, Bl[tt][1], z);
      z = mfma16(Ar0, Br[tt][0], z);
      z = mfma16(Ar1, Br[tt][1], z);
      z = mfma16(Ae0, Be[tt][0], z);
      acc[tt] = mfma16(Ae1, Be[tt][1], z);
    }
#pragma unroll
    for (int r = 0; r < 4; ++r) {
      float pd = 0.f;
#pragma unroll
      for (int tt = 0; tt < 4; ++tt) {
        float m = acc[tt][r] + bv[tt];
        m = fmaxf(m, 0.2f * m);           // leaky: max(x, 0.2x)
        pd += m * av[tt];
      }
      pd += __shfl_xor(pd, 1, 64);
      pd += __shfl_xor(pd, 2, 64);
      pd += __shfl_xor(pd, 4, 64);
      pd += __shfl_xor(pd, 8, 64);
      if (q == 0) lg[(size_t)(pb + t * 16 + g * 4 + r) * 4 + w] = pd;
    }
  }
}

// fused segment-softmax + aggregation + folded MFMA update.
__global__ __launch_bounds__(256) void k_aggupd(
    const short* __restrict__ hbin, const float* __restrict__ lg,
    const int* __restrict__ row_ptr, const int* __restrict__ psrc,
    const short* __restrict__ updf, const float* __restrict__ bl,
    const float* __restrict__ bias, float* __restrict__ h, short* __restrict__ hbout) {
  __shared__ short agls[16 * 264];      // 264 = 256 + 8 pad
  __shared__ float albuf[4][260];       // per-wave 64-edge x 4-head exp window
  int tid = threadIdx.x, lane = tid & 63, w = tid >> 6;
  int q = lane & 15, g = lane >> 4;
  int n0 = blockIdx.x * 16;
  int i16 = lane & 15, h4 = lane >> 4;  // h4 doubles as 4-wide edge-group id
  float* alw = albuf[w];
#pragma unroll 1
  for (int i = 0; i < 4; ++i) {
    int n = n0 + w * 4 + i;
    int s0 = row_ptr[n], s1 = row_ptr[n + 1];
    // max per head (lane group h4)
    float m = -3.4e38f;
    for (int p = s0 + i16; p < s1; p += 16) m = fmaxf(m, lg[(size_t)p * 4 + h4]);
#pragma unroll
    for (int o = 1; o < 16; o <<= 1) m = fmaxf(m, __shfl_xor(m, o, 64));
    // windowed gather: exp once per (edge,head) -> LDS; partial sum accumulated inline
    float sum = 0.f;
    float acc[4][4];
#pragma unroll
    for (int hh = 0; hh < 4; ++hh)
#pragma unroll
      for (int j = 0; j < 4; ++j) acc[hh][j] = 0.f;
    for (int wst = s0; wst < s1; wst += 64) {
      int wend = wst + 64 < s1 ? wst + 64 : s1;
#pragma unroll
      for (int k = 0; k < 4; ++k) {
        int p = wst + k * 16 + i16;
        float e = (p < s1) ? __expf(lg[(size_t)p * 4 + h4] - m) : 0.f;
        alw[(k * 16 + i16) * 4 + h4] = e;
        sum += e;
      }
      asm volatile("s_waitcnt lgkmcnt(0)" ::: "memory");
      for (int p0 = wst; p0 < wend; p0 += 4) {
        int p = p0 + h4;
        bool v = p < wend;
        int pc = v ? p : wend - 1;
        int sp = psrc[pc];
        float4 al = *(const float4*)&alw[(pc - wst) * 4];
        short4 hv = *(const short4*)(hbin + (size_t)sp * 64 + i16 * 4);
        if (!v) { al.x = 0.f; al.y = 0.f; al.z = 0.f; al.w = 0.f; }
        float hf0 = b2f(hv.x), hf1 = b2f(hv.y), hf2 = b2f(hv.z), hf3 = b2f(hv.w);
        acc[0][0] += al.x * hf0; acc[0][1] += al.x * hf1;
        acc[0][2] += al.x * hf2; acc[0][3] += al.x * hf3;
        acc[1][0] += al.y * hf0; acc[1][1] += al.y * hf1;
        acc[1][2] += al.y * hf2; acc[1][3] += al.y * hf3;
        acc[2][0] += al.z * hf0; acc[2][1] += al.z * hf1;
        acc[2][2] += al.z * hf2; acc[2][3] += al.z * hf3;
        acc[3][0] += al.w * hf0; acc[3][1] += al.w * hf1;
        acc[3][2] += al.w * hf2; acc[3][3] += al.w * hf3;
      }
    }
    // reduce sum over 16 i16-lanes (per head group)
#pragma unroll
    for (int o = 1; o < 16; o <<= 1) sum += __shfl_xor(sum, o, 64);
    float inv = 1.f / sum;
    float ih4[4];
#pragma unroll
    for (int hh = 0; hh < 4; ++hh) ih4[hh] = __shfl(inv, hh * 16, 64);
    // reduce acc over 4 edge-groups (lane>>4): 2 levels
#pragma unroll
    for (int hh = 0; hh < 4; ++hh)
#pragma unroll
      for (int j = 0; j < 4; ++j) {
        acc[hh][j] += __shfl_xor(acc[hh][j], 16, 64);
        acc[hh][j] += __shfl_xor(acc[hh][j], 32, 64);
      }
    if (lane < 16) {
#pragma unroll
      for (int hh = 0; hh < 4; ++hh) {
        short4 o4;
        o4.x = f2bf(acc[hh][0] * ih4[hh]);
        o4.y = f2bf(acc[hh][1] * ih4[hh]);
        o4.z = f2bf(acc[hh][2] * ih4[hh]);
        o4.w = f2bf(acc[hh][3] * ih4[hh]);
        *(short4*)(agls + (w * 4 + i) * 264 + hh * 64 + i16 * 4) = o4;
      }
    }
  }
  __syncthreads();
  // MFMA update: A row = node q (agg, K=256), B = folded weights; out cols w*16..+16
  const short* arow = agls + q * 264;
  f32x4 z = {0.f, 0.f, 0.f, 0.f};
#pragma unroll
  for (int kh = 0; kh < 8; ++kh) {
    bf16x8 A = *(const bf16x8*)(arow + kh * 32 + g * 8);
    bf16x8 B = *(const bf16x8*)(updf + ((size_t)(w * 8 + kh) * 64 + lane) * 8);
    z = mfma16(A, B, z);
  }
  int c = w * 16 + q;
  float bf = 0.25f * (bl[c] + bl[64 + c] + bl[128 + c] + bl[192 + c]) + bias[c];
#pragma unroll
  for (int r = 0; r < 4; ++r) {
    int n = n0 + g * 4 + r;
    float nh = h[(size_t)n * 64 + c] + fmaxf(z[r] + bf, 0.f);
    h[(size_t)n * 64 + c] = nh;
    hbout[(size_t)n * 64 + c] = f2bf(nh);
  }
}

// ---------------- fused output heads ----------------
__global__ __launch_bounds__(256) void k_heads(
    const short* __restrict__ hb, const short* __restrict__ efc,
    const int* __restrict__ src, const int* __restrict__ dst,
    const int* __restrict__ pos, const short* __restrict__ eclsf,
    const float* __restrict__ b1, const float* __restrict__ w2,
    const float* __restrict__ b2,
    const float* __restrict__ h, const float* __restrict__ ow1,
    const float* __restrict__ ob1, const float* __restrict__ ow2,
    const float* __restrict__ ob2, float* __restrict__ out) {
  __shared__ __align__(16) char smraw[25600];
  int tid = threadIdx.x;
  int w = tid >> 6, lane = tid & 63, q = lane & 15, g = lane >> 4;
  if (blockIdx.x < ECLS_BLK) {
    short* smA = (short*)smraw;                  // 3 planes x 64 edges x 64 shorts = 24 KB
    float* sm = (float*)(smraw + 24576);         // 256 floats
    int e0b = blockIdx.x * 64;
    int id6[6];
#pragma unroll
    for (int j = 0; j < 6; ++j) {
      int s = (w * 6 + j) * 64 + lane;           // 0..1535
      int r = s >> 9, e = (s >> 3) & 63;
      int eg = e0b + e;
      id6[j] = (r == 0) ? src[eg] : (r == 1) ? dst[eg] : pos[eg];
    }
#pragma unroll
    for (int j = 0; j < 6; ++j) {
      int s = (w * 6 + j) * 64 + lane;
      int r = s >> 9, e = (s >> 3) & 63, c16 = s & 7;
      int cs = (c16 ^ (e & 7)) * 8;              // pre-swizzled short offset
      const short* gp = ((r == 2) ? efc : hb) + (size_t)id6[j] * 64 + cs;
      gl16(gp, &smA[(size_t)s * 8]);
    }
    int c = w * 16 + q;
    bf16x8 Bf[6];
#pragma unroll
    for (int kh = 0; kh < 6; ++kh)
      Bf[kh] = *(const bf16x8*)(eclsf + ((size_t)(w * 6 + kh) * 64 + lane) * 8);
    float b1v = b1[c], w2v = w2[c], b2v = b2[0];
    __syncthreads();  // drains staging vmcnt
    int xa = (g ^ (q & 7)) * 8;
    int xb = ((4 + g) ^ (q & 7)) * 8;
#pragma unroll
    for (int tile = 0; tile < 4; ++tile) {
      const short* rp = smA + (tile * 16 + q) * 64;
      f32x4 acc = {0.f, 0.f, 0.f, 0.f};
      acc = mfma16(*(const bf16x8*)(rp + xa), Bf[0], acc);
      acc = mfma16(*(const bf16x8*)(rp + xb), Bf[1], acc);
      acc = mfma16(*(const bf16x8*)(rp + 4096 + xa), Bf[2], acc);
      acc = mfma16(*(const bf16x8*)(rp + 4096 + xb), Bf[3], acc);
      acc = mfma16(*(const bf16x8*)(rp + 8192 + xa), Bf[4], acc);
      acc = mfma16(*(const bf16x8*)(rp + 8192 + xb), Bf[5], acc);
#pragma unroll
      for (int r = 0; r < 4; ++r) {
        float hv = fmaxf(acc[r] + b1v, 0.f) * w2v;
        hv += __shfl_xor(hv, 1, 64);
        hv += __shfl_xor(hv, 2, 64);
        hv += __shfl_xor(hv, 4, 64);
        hv += __shfl_xor(hv, 8, 64);
        if (q == 0) sm[tile * 64 + w * 16 + g * 4 + r] = hv;
      }
    }
    __syncthreads();
    if (tid < 64) {
      int tile = tid >> 4, e = tid & 15;
      float t = sm[tile * 64 + e] + sm[tile * 64 + 16 + e] +
                sm[tile * 64 + 32 + e] + sm[tile * 64 + 48 + e] + b2v;
      out[e0b + tile * 16 + e] = 1.f / (1.f + __expf(-t));
    }
  } else {
    // ---- offset regressor ----
    float* w1l = (float*)smraw;  // 4096 floats
#pragma unroll
    for (int qq = 0; qq < 16; ++qq) w1l[qq * 256 + tid] = ow1[qq * 256 + tid];
    __syncthreads();
    int n = (blockIdx.x - ECLS_BLK) * 4 + w;
    float hr = h[n * 64 + lane];
    float hid = ob1[lane];
#pragma unroll
    for (int k = 0; k < 64; ++k) hid += bcast(hr, k) * w1l[k * 64 + lane];
    hid = fmaxf(hid, 0.f);
    float p0 = wred_sum(hid * ow2[lane * 2]);
    float p1 = wred_sum(hid * ow2[lane * 2 + 1]);
    if (lane == 0) {
      out[N_EDGES + n * 2] = p0 + ob2[0];
      out[N_EDGES + n * 2 + 1] = p1 + ob2[1];
    }
  }
}

// ---------------- launcher ----------------

extern "C" void kernel_launch(void* const* d_in, const int* in_sizes, int n_in,
                              void* d_out, int out_size, void* d_ws, size_t ws_size,
                              hipStream_t stream) {
  const float* x     = (const float*)d_in[0];
  const int*   eidx  = (const int*)d_in[1];
  const float* eattr = (const float*)d_in[2];
  const float* ne_w1 = (const float*)d_in[3];
  const float* ne_b1 = (const float*)d_in[4];
  const float* ne_w2 = (const float*)d_in[5];
  const float* ne_b2 = (const float*)d_in[6];
  const float* ee_w1 = (const float*)d_in[7];
  const float* ee_b1 = (const float*)d_in[8];
  const float* ee_w2 = (const float*)d_in[9];
  const float* ee_b2 = (const float*)d_in[10];
  const float* cv_wl = (const float*)d_in[11];
  const float* cv_bl = (const float*)d_in[12];
  const float* cv_wr = (const float*)d_in[13];
  const float* cv_br = (const float*)d_in[14];
  const float* cv_we = (const float*)d_in[15];
  const float* cv_att = (const float*)d_in[16];
  const float* cv_bias = (const float*)d_in[17];
  const float* ec_w1 = (const float*)d_in[18];
  const float* ec_b1 = (const float*)d_in[19];
  const float* ec_w2 = (const float*)d_in[20];
  const float* ec_b2 = (const float*)d_in[21];
  const float* or_w1 = (const float*)d_in[22];
  const float* or_b1 = (const float*)d_in[23];
  const float* or_w2 = (const float*)d_in[24];
  const float* or_b2 = (const float*)d_in[25];

  const int* src = eidx;
  const int* dst = eidx + N_EDGES;

  // workspace layout
  float* fws = (float*)d_ws;
  size_t o = 0;
  float* h  = fws + o; o += (size_t)N_NODES * 64;
  float* lg = fws + o; o += (size_t)EP * 4;   // layout [p][4]
  short* sws = (short*)(fws + o);
  size_t so = 0;
  short* hb0  = sws + so; so += (size_t)N_NODES * 64;
  short* hb1  = sws + so; so += (size_t)N_NODES * 64;
  short* efc  = sws + so; so += (size_t)EP * 64;
  short* wlf  = sws + so; so += 3 * PREP_SEG;
  short* wrf  = sws + so; so += 3 * PREP_SEG;
  short* wef  = sws + so; so += 3 * PREP_SEG;
  short* updf = sws + so; so += 3 * PREP_SEG;
  short* eclsf = sws + so; so += 12288;
  short* encf  = sws + so; so += 4096;
  int* iws = (int*)(sws + so + (so & 1));
  int* row_ptr = iws;
  int* col_idx = iws + (N_NODES + 64);
  int* pdst = col_idx + EP;
  int* psrc = pdst + EP;
  int* pos  = psrc + EP;
  int* cnt  = pos + EP;
  int* fill = cnt + N_NODES;
  int* bsum = fill + N_NODES;

  float* out = (float*)d_out;

  // weight fragment prep + cnt/fill zeroing
  k_prep_all<<<(12 * PREP_SEG + 12288 + 4096 + 2 * N_NODES + 255) / 256, 256, 0, stream>>>(
      cv_wl, cv_wr, cv_we, ec_w1, ee_w2, wlf, wrf, wef, updf, eclsf, encf, cnt, fill);

  // CSR build
  k_count<<<(N_EDGES + 255) / 256, 256, 0, stream>>>(dst, cnt);
  k_scan1<<<NBLK, 256, 0, stream>>>(cnt, row_ptr, bsum);
  k_scan23<<<1, 256, 0, stream>>>(bsum, row_ptr);
  k_scatter<<<(EP + 255) / 256, 256, 0, stream>>>(dst, row_ptr, fill, col_idx, pdst);
  k_sortp<<<(N_NODES + 255) / 256, 256, 0, stream>>>(row_ptr, col_idx, src, psrc, pos);

  // encoders (edge blocks + node blocks fused)
  k_enc<<<EENC_BLK + N_NODES / 4, 256, 0, stream>>>(
      x, ne_w1, ne_b1, ne_w2, ne_b2, eattr, ee_w1, ee_b1, encf, ee_b2, pos, efc, h, hb0);
  k_loop_feat<<<N_NODES / 4, 256, 0, stream>>>(row_ptr, efc);

  // 3 GATv2 layers (hb ping-pong)
  short* hcur = hb0;
  short* hnxt = hb1;
  for (int l = 0; l < 3; ++l) {
    const float* bl = cv_bl + (size_t)l * 256;
    const float* br = cv_br + (size_t)l * 256;
    const float* at = cv_att + (size_t)l * 256;
    const float* bi = cv_bias + (size_t)l * 64;
    k_elog<<<EP / 96, 256, 0, stream>>>(hcur, efc, psrc, pdst,
                                        wlf + (size_t)l * PREP_SEG,
                                        wrf + (size_t)l * PREP_SEG,
                                        wef + (size_t)l * PREP_SEG, bl, br, at, lg);
    k_aggupd<<<N_NODES / 16, 256, 0, stream>>>(hcur, lg, row_ptr, psrc,
                                               updf + (size_t)l * PREP_SEG, bl, bi, h, hnxt);
    short* tmp = hcur; hcur = hnxt; hnxt = tmp;
  }

  // fused heads (final hb = hcur)
  k_heads<<<ECLS_BLK + N_NODES / 4, 256, 0, stream>>>(
      hcur, efc, src, dst, pos, eclsf, ec_b1, ec_w2, ec_b2,
      h, or_w1, or_b1, or_w2, or_b2, out);
}

// Round 15
// 278.639 us; speedup vs baseline: 1.0703x; 1.0184x over previous
//
#include <hip/hip_runtime.h>

#define N_NODES 20000
#define N_EDGES 160000
#define EP (N_EDGES + N_NODES)   // 180000 edges incl. self loops
#define NBLK ((N_NODES + 255) / 256)  // 79
#define PREP_SEG 16384
#define EENC_BLK (N_EDGES / 64)  // 2500 edge-encoder blocks
#define ECLS_BLK (N_EDGES / 64)  // 2500 edge-classifier blocks

typedef __attribute__((ext_vector_type(8))) short bf16x8;
typedef __attribute__((ext_vector_type(4))) float f32x4;

__device__ __forceinline__ short f2bf(float f) {
  unsigned u = __float_as_uint(f);
  unsigned r = (u + 0x7FFFu + ((u >> 16) & 1u)) >> 16;  // RNE
  return (short)r;
}
__device__ __forceinline__ float b2f(short s) {
  return __uint_as_float(((unsigned)(unsigned short)s) << 16);
}

__device__ __forceinline__ f32x4 mfma16(bf16x8 a, bf16x8 b, f32x4 c) {
  return __builtin_amdgcn_mfma_f32_16x16x32_bf16(a, b, c, 0, 0, 0);
}

__device__ __forceinline__ float bcast(float v, int k) {
  return __uint_as_float(__builtin_amdgcn_readlane(__float_as_uint(v), k));
}

__device__ __forceinline__ float wred_sum(float v) {
#pragma unroll
  for (int o = 32; o > 0; o >>= 1) v += __shfl_xor(v, o, 64);
  return v;
}

// async gather: per-lane global src -> linear LDS (base + lane*16)
__device__ __forceinline__ void gl16(const short* g, short* l) {
  __builtin_amdgcn_global_load_lds(
      (const __attribute__((address_space(1))) void*)g,
      (__attribute__((address_space(3))) void*)l, 16, 0, 0);
}

// ---------------- weight fragment prep + cnt/fill zeroing ----------------
__global__ void k_prep_all(const float* __restrict__ cv_wl, const float* __restrict__ cv_wr,
                           const float* __restrict__ cv_we, const float* __restrict__ ec_w1,
                           const float* __restrict__ ee_w2,
                           short* __restrict__ wlf, short* __restrict__ wrf,
                           short* __restrict__ wef, short* __restrict__ updf,
                           short* __restrict__ eclsf, short* __restrict__ encf,
                           int* __restrict__ cnt, int* __restrict__ fill) {
  int i = blockIdx.x * 256 + threadIdx.x;
  if (i < 12 * PREP_SEG) {
    int grp = i / PREP_SEG;
    int r = i % PREP_SEG;
    int kind = grp / 3, l = grp % 3;
    int j = r & 7, lane = (r >> 3) & 63;
    int q = lane & 15, g = lane >> 4;
    if (kind < 3) {  // wl/wr/we : [64,256], out cols c = w*64+t*16+q
      int kh = (r >> 9) & 1, t = (r >> 10) & 3, w = r >> 12;
      int k = kh * 32 + g * 8 + j, c = w * 64 + t * 16 + q;
      const float* W = (kind == 0 ? cv_wl : kind == 1 ? cv_wr : cv_we) + (size_t)l * 64 * 256;
      short* out = (kind == 0 ? wlf : kind == 1 ? wrf : wef) + (size_t)l * PREP_SEG;
      out[r] = f2bf(W[k * 256 + c]);
    } else {        // folded update: Wfold[h*64+kk][c] = 0.25*wl[kk][h*64+c]
      int kh = (r >> 9) & 7, w = r >> 12;
      int k = kh * 32 + g * 8 + j, c = w * 16 + q;
      const float* W = cv_wl + (size_t)l * 64 * 256;
      updf[(size_t)l * PREP_SEG + r] = f2bf(0.25f * W[(k & 63) * 256 + (k >> 6) * 64 + c]);
    }
  } else if (i < 12 * PREP_SEG + 12288) {  // ec_w1 [192,64], 6 k-frags
    int r = i - 12 * PREP_SEG;
    int j = r & 7, lane = (r >> 3) & 63, f = r >> 9;
    int w = f / 6, kh = f % 6;
    int q = lane & 15, g = lane >> 4;
    int k = kh * 32 + g * 8 + j, c = w * 16 + q;
    eclsf[r] = f2bf(ec_w1[(size_t)k * 64 + c]);
  } else if (i < 12 * PREP_SEG + 12288 + 4096) {  // ee_w2 [64,64], 2 k-frags
    int r = i - 12 * PREP_SEG - 12288;
    int j = r & 7, lane = (r >> 3) & 63, f = r >> 9;
    int w = f >> 1, kh = f & 1;
    int q = lane & 15, g = lane >> 4;
    int k = kh * 32 + g * 8 + j, c = w * 16 + q;
    encf[r] = f2bf(ee_w2[(size_t)k * 64 + c]);
  } else {
    int r = i - (12 * PREP_SEG + 12288 + 4096);
    if (r < N_NODES) cnt[r] = 0;
    else if (r < 2 * N_NODES) fill[r - N_NODES] = 0;
  }
}

// ---------------- CSR build ----------------

__global__ void k_count(const int* __restrict__ dst, int* __restrict__ cnt) {
  int i = blockIdx.x * blockDim.x + threadIdx.x;
  if (i < N_EDGES) atomicAdd(&cnt[dst[i]], 1);
}

__global__ void k_scan1(const int* __restrict__ cnt, int* __restrict__ row_ptr,
                        int* __restrict__ bsum) {
  __shared__ int sh[256];
  int t = threadIdx.x, b = blockIdx.x, i = b * 256 + t;
  int v = (i < N_NODES) ? cnt[i] + 1 : 0;  // +1 self loop
  sh[t] = v;
  __syncthreads();
#pragma unroll
  for (int off = 1; off < 256; off <<= 1) {
    int x = (t >= off) ? sh[t - off] : 0;
    __syncthreads();
    sh[t] += x;
    __syncthreads();
  }
  if (i < N_NODES) row_ptr[i + 1] = sh[t];
  if (t == 255) bsum[b] = sh[255];
}

// scan of block sums + offset add fused (one block)
__global__ void k_scan23(const int* __restrict__ bsum, int* __restrict__ row_ptr) {
  __shared__ int sh[256];
  __shared__ int boffs[128];
  int t = threadIdx.x;
  int v = (t < NBLK) ? bsum[t] : 0;
  sh[t] = v;
  __syncthreads();
#pragma unroll
  for (int off = 1; off < 256; off <<= 1) {
    int x = (t >= off) ? sh[t - off] : 0;
    __syncthreads();
    sh[t] += x;
    __syncthreads();
  }
  if (t < NBLK) boffs[t] = sh[t] - v;  // exclusive
  __syncthreads();
  for (int i = t; i < N_NODES; i += 256) row_ptr[i + 1] += boffs[i >> 8];
  if (t == 0) row_ptr[0] = 0;
}

__global__ void k_scatter(const int* __restrict__ dst, const int* __restrict__ row_ptr,
                          int* __restrict__ fill, int* __restrict__ col_idx,
                          int* __restrict__ pdst) {
  int i = blockIdx.x * blockDim.x + threadIdx.x;
  if (i >= EP) return;
  int d = (i < N_EDGES) ? dst[i] : (i - N_EDGES);
  int p = row_ptr[d] + atomicAdd(&fill[d], 1);
  col_idx[p] = i;
  pdst[p] = d;
}

// sort + psrc/pos derivation fused
__global__ void k_sortp(const int* __restrict__ row_ptr, int* __restrict__ col_idx,
                        const int* __restrict__ src, int* __restrict__ psrc,
                        int* __restrict__ pos) {
  int n = blockIdx.x * blockDim.x + threadIdx.x;
  if (n >= N_NODES) return;
  int s = row_ptr[n], e = row_ptr[n + 1];
  for (int i = s + 1; i < e; ++i) {
    int v = col_idx[i];
    int j = i - 1;
    while (j >= s && col_idx[j] > v) { col_idx[j + 1] = col_idx[j]; --j; }
    col_idx[j + 1] = v;
  }
  for (int i = s; i < e; ++i) {
    int eid = col_idx[i];
    pos[eid] = i;
    psrc[i] = (eid < N_EDGES) ? src[eid] : (eid - N_EDGES);
  }
}

// ---------------- fused encoders (edge blocks first, then node blocks) ----------------

__global__ __launch_bounds__(256) void k_enc(
    const float* __restrict__ x,
    const float* __restrict__ nw1, const float* __restrict__ nb1,
    const float* __restrict__ nw2, const float* __restrict__ nb2,
    const float* __restrict__ ea,
    const float* __restrict__ ew1, const float* __restrict__ eb1,
    const short* __restrict__ encf, const float* __restrict__ eb2,
    const int* __restrict__ pos, short* __restrict__ efc,
    float* __restrict__ h, short* __restrict__ hb) {
  __shared__ __align__(16) char smraw[18432];
  int tid = threadIdx.x;
  int lane = tid & 63, w = tid >> 6, q = lane & 15, g = lane >> 4;
  if (blockIdx.x < EENC_BLK) {
    // ---- edge encoder: 64 edges/block ----
    short* hs = (short*)smraw;                 // 64*72 shorts = 9216B
    short* ot = (short*)(smraw + 9216);        // 64*64 shorts = 8192B
    int* ps = (int*)(smraw + 17408);           // 64 ints = 256B
    float* easm = (float*)(smraw + 17664);     // 192 floats = 768B
    int e0 = blockIdx.x * 64;
    if (tid < 64) ps[tid] = pos[e0 + tid];
    if (tid < 192) easm[tid] = ea[(size_t)e0 * 3 + tid];  // coalesced stage
    float w1a = ew1[lane], w1b = ew1[64 + lane], w1c = ew1[128 + lane], b1v = eb1[lane];
    __syncthreads();
#pragma unroll
    for (int t = 0; t < 16; ++t) {
      int e = w * 16 + t;
      float a0 = easm[e * 3], a1 = easm[e * 3 + 1], a2 = easm[e * 3 + 2];  // broadcasts
      float hid = fmaxf(a0 * w1a + a1 * w1b + a2 * w1c + b1v, 0.f);
      hs[e * 72 + lane] = f2bf(hid);
    }
    bf16x8 A0 = *(const bf16x8*)&hs[(w * 16 + q) * 72 + g * 8];
    bf16x8 A1 = *(const bf16x8*)&hs[(w * 16 + q) * 72 + 32 + g * 8];
#pragma unroll
    for (int cc = 0; cc < 4; ++cc) {
      bf16x8 B0 = *(const bf16x8*)(encf + ((size_t)(cc * 2 + 0) * 64 + lane) * 8);
      bf16x8 B1 = *(const bf16x8*)(encf + ((size_t)(cc * 2 + 1) * 64 + lane) * 8);
      f32x4 z = {0.f, 0.f, 0.f, 0.f};
      z = mfma16(A0, B0, z);
      z = mfma16(A1, B1, z);
      float bv = eb2[cc * 16 + q];
#pragma unroll
      for (int r = 0; r < 4; ++r)
        ot[(w * 16 + g * 4 + r) * 64 + cc * 16 + q] = f2bf(z[r] + bv);
    }
    __syncthreads();
    int row = tid >> 2, part = tid & 3;
    short* d = efc + (size_t)ps[row] * 64 + part * 16;
    const short* s = ot + row * 64 + part * 16;
    *(bf16x8*)d = *(const bf16x8*)s;
    *(bf16x8*)(d + 8) = *(const bf16x8*)(s + 8);
  } else {
    // ---- node encoder: 4 nodes/block ----
    float* w2l = (float*)smraw;              // 4096 floats
#pragma unroll
    for (int qq = 0; qq < 16; ++qq) w2l[qq * 256 + tid] = nw2[qq * 256 + tid];
    __syncthreads();
    int n = (blockIdx.x - EENC_BLK) * 4 + w;
    float x0 = x[n * 2], x1 = x[n * 2 + 1];
    float hid = fmaxf(x0 * nw1[lane] + x1 * nw1[64 + lane] + nb1[lane], 0.f);
    float out = nb2[lane];
#pragma unroll
    for (int k = 0; k < 64; ++k) out += bcast(hid, k) * w2l[k * 64 + lane];
    h[n * 64 + lane] = out;
    hb[n * 64 + lane] = f2bf(out);
  }
}

// self-loop row (last CSR slot per node) = mean of node's original-edge rows; 8-row parallel
__global__ __launch_bounds__(256) void k_loop_feat(
    const int* __restrict__ row_ptr, short* __restrict__ efc) {
  int tid = threadIdx.x, lane = tid & 63, w = tid >> 6;
  int n = blockIdx.x * 4 + w;
  int s = row_ptr[n], e1 = row_ptr[n + 1];
  int r8 = lane >> 3, oct = lane & 7;
  float acc[8];
#pragma unroll
  for (int j = 0; j < 8; ++j) acc[j] = 0.f;
  for (int p0 = s; p0 < e1 - 1; p0 += 8) {
    int p = p0 + r8;
    if (p < e1 - 1) {
      bf16x8 A = *(const bf16x8*)(efc + (size_t)p * 64 + oct * 8);
#pragma unroll
      for (int j = 0; j < 8; ++j) acc[j] += b2f(A[j]);
    }
  }
#pragma unroll
  for (int j = 0; j < 8; ++j) {
    acc[j] += __shfl_xor(acc[j], 8, 64);
    acc[j] += __shfl_xor(acc[j], 16, 64);
    acc[j] += __shfl_xor(acc[j], 32, 64);
  }
  int c = e1 - 1 - s;
  float invc = 1.f / (float)(c > 0 ? c : 1);
  if (lane < 8) {
    bf16x8 o8;
#pragma unroll
    for (int j = 0; j < 8; ++j) o8[j] = f2bf(acc[j] * invc);
    *(bf16x8*)(efc + (size_t)(e1 - 1) * 64 + lane * 8) = o8;
  }
}

// ---------------- GAT layer ----------------

// r15: 128 CSR slots/block (8 tiles of 16). Stage {hb[src], efc} to LDS
// (32 KB); hb[dst] direct from global; single barrier; full-unroll compute.
// Bigger tile amortizes the 24 B-fragment loads + epilogue constants over
// 33% more edges; grid 1875 -> 1407. Tail clamped + guarded.
__global__ __launch_bounds__(256) void k_elog(
    const short* __restrict__ hb, const short* __restrict__ efc,
    const int* __restrict__ psrc, const int* __restrict__ pdst,
    const short* __restrict__ wlf, const short* __restrict__ wrf,
    const short* __restrict__ wef, const float* __restrict__ bl,
    const float* __restrict__ br, const float* __restrict__ att, float* __restrict__ lg) {
  __shared__ __align__(16) short smA[128 * 2 * 64];  // 32 KB
  int tid = threadIdx.x;
  int w = tid >> 6, lane = tid & 63, q = lane & 15, g = lane >> 4;
  int cbase = w * 64;
  int pb = blockIdx.x * 128;

  // ---- staging: wave w issues 8 x 1KB gather/stream-to-LDS ----
  // slot s: t = s>>8, r = (s>>7)&1 (0=src,1=ef), e = (s>>3)&15, c16 = s&7
  int id8[8];
#pragma unroll
  for (int j = 0; j < 8; ++j) {
    int s = (w * 8 + j) * 64 + lane;      // 0..2047
    int t = s >> 8, s2 = s & 255;
    int r = s2 >> 7, e = (s2 >> 3) & 15;
    int pe = pb + t * 16 + e;
    pe = pe < EP ? pe : EP - 1;
    id8[j] = (r == 0) ? psrc[pe] : pe;
  }
#pragma unroll
  for (int j = 0; j < 8; ++j) {
    int s = (w * 8 + j) * 64 + lane;
    int s2 = s & 255;
    int r = s2 >> 7, e = (s2 >> 3) & 15, c16 = s & 7;
    int cs = (c16 ^ (e & 7)) * 8;         // pre-swizzled short offset
    const short* gp = ((r == 1) ? efc : hb) + (size_t)id8[j] * 64 + cs;
    gl16(gp, &smA[(size_t)s * 8]);
  }

  // dst indices for direct loads
  int nd[8];
#pragma unroll
  for (int t = 0; t < 8; ++t) {
    int pe = pb + t * 16 + q;
    nd[t] = pdst[pe < EP ? pe : EP - 1];
  }

  // ---- B fragments (overlap with staging latency) ----
  bf16x8 Bl[4][2], Br[4][2], Be[4][2];
  float av[4], bv[4];
#pragma unroll
  for (int t = 0; t < 4; ++t) {
    int c = cbase + t * 16 + q;
    av[t] = att[c];
    bv[t] = bl[c] + br[c];
#pragma unroll
    for (int kh = 0; kh < 2; ++kh) {
      size_t fo = ((size_t)((w * 4 + t) * 2 + kh) * 64 + lane) * 8;
      Bl[t][kh] = *(const bf16x8*)(wlf + fo);
      Br[t][kh] = *(const bf16x8*)(wrf + fo);
      Be[t][kh] = *(const bf16x8*)(wef + fo);
    }
  }
  __syncthreads();  // drains staging vmcnt; all tiles visible

  int xa = (g ^ (q & 7)) * 8;
  int xb = ((4 + g) ^ (q & 7)) * 8;
  int rowoff = q * 64;                    // shorts
#pragma unroll
  for (int t = 0; t < 8; ++t) {
    const short* base = smA + t * 2048;
    const short* ar = hb + (size_t)nd[t] * 64;
    bf16x8 As0 = *(const bf16x8*)(base + rowoff + xa);
    bf16x8 As1 = *(const bf16x8*)(base + rowoff + xb);
    bf16x8 Ar0 = *(const bf16x8*)(ar + g * 8);
    bf16x8 Ar1 = *(const bf16x8*)(ar + 32 + g * 8);
    bf16x8 Ae0 = *(const bf16x8*)(base + 1024 + rowoff + xa);
    bf16x8 Ae1 = *(const bf16x8*)(base + 1024 + rowoff + xb);
    f32x4 acc[4];
#pragma unroll
    for (int tt = 0; tt < 4; ++tt) {
      f32x4 z = {0.f, 0.f, 0.f, 0.f};
      z = mfma16(As0, Bl[tt][0], z);
      z = mfma16(As1, Bl[tt][1], z);
      z = mfma16(Ar0, Br[tt][0], z);
      z = mfma16(Ar1, Br[tt][1], z);
      z = mfma16(Ae0, Be[tt][0], z);
      acc[tt] = mfma16(Ae1, Be[tt][1], z);
    }
#pragma unroll
    for (int r = 0; r < 4; ++r) {
      float pd = 0.f;
#pragma unroll
      for (int tt = 0; tt < 4; ++tt) {
        float m = acc[tt][r] + bv[tt];
        m = fmaxf(m, 0.2f * m);           // leaky: max(x, 0.2x)
        pd += m * av[tt];
      }
      pd += __shfl_xor(pd, 1, 64);
      pd += __shfl_xor(pd, 2, 64);
      pd += __shfl_xor(pd, 4, 64);
      pd += __shfl_xor(pd, 8, 64);
      int pstore = pb + t * 16 + g * 4 + r;
      if (q == 0 && pstore < EP) lg[(size_t)pstore * 4 + w] = pd;
    }
  }
}

// fused segment-softmax + aggregation + folded MFMA update.
__global__ __launch_bounds__(256) void k_aggupd(
    const short* __restrict__ hbin, const float* __restrict__ lg,
    const int* __restrict__ row_ptr, const int* __restrict__ psrc,
    const short* __restrict__ updf, const float* __restrict__ bl,
    const float* __restrict__ bias, float* __restrict__ h, short* __restrict__ hbout) {
  __shared__ short agls[16 * 264];      // 264 = 256 + 8 pad
  __shared__ float albuf[4][260];       // per-wave 64-edge x 4-head exp window
  int tid = threadIdx.x, lane = tid & 63, w = tid >> 6;
  int q = lane & 15, g = lane >> 4;
  int n0 = blockIdx.x * 16;
  int i16 = lane & 15, h4 = lane >> 4;  // h4 doubles as 4-wide edge-group id
  float* alw = albuf[w];
#pragma unroll 1
  for (int i = 0; i < 4; ++i) {
    int n = n0 + w * 4 + i;
    int s0 = row_ptr[n], s1 = row_ptr[n + 1];
    // max per head (lane group h4)
    float m = -3.4e38f;
    for (int p = s0 + i16; p < s1; p += 16) m = fmaxf(m, lg[(size_t)p * 4 + h4]);
#pragma unroll
    for (int o = 1; o < 16; o <<= 1) m = fmaxf(m, __shfl_xor(m, o, 64));
    // windowed gather: exp once per (edge,head) -> LDS; partial sum accumulated inline
    float sum = 0.f;
    float acc[4][4];
#pragma unroll
    for (int hh = 0; hh < 4; ++hh)
#pragma unroll
      for (int j = 0; j < 4; ++j) acc[hh][j] = 0.f;
    for (int wst = s0; wst < s1; wst += 64) {
      int wend = wst + 64 < s1 ? wst + 64 : s1;
#pragma unroll
      for (int k = 0; k < 4; ++k) {
        int p = wst + k * 16 + i16;
        float e = (p < s1) ? __expf(lg[(size_t)p * 4 + h4] - m) : 0.f;
        alw[(k * 16 + i16) * 4 + h4] = e;
        sum += e;
      }
      asm volatile("s_waitcnt lgkmcnt(0)" ::: "memory");
      for (int p0 = wst; p0 < wend; p0 += 4) {
        int p = p0 + h4;
        bool v = p < wend;
        int pc = v ? p : wend - 1;
        int sp = psrc[pc];
        float4 al = *(const float4*)&alw[(pc - wst) * 4];
        short4 hv = *(const short4*)(hbin + (size_t)sp * 64 + i16 * 4);
        if (!v) { al.x = 0.f; al.y = 0.f; al.z = 0.f; al.w = 0.f; }
        float hf0 = b2f(hv.x), hf1 = b2f(hv.y), hf2 = b2f(hv.z), hf3 = b2f(hv.w);
        acc[0][0] += al.x * hf0; acc[0][1] += al.x * hf1;
        acc[0][2] += al.x * hf2; acc[0][3] += al.x * hf3;
        acc[1][0] += al.y * hf0; acc[1][1] += al.y * hf1;
        acc[1][2] += al.y * hf2; acc[1][3] += al.y * hf3;
        acc[2][0] += al.z * hf0; acc[2][1] += al.z * hf1;
        acc[2][2] += al.z * hf2; acc[2][3] += al.z * hf3;
        acc[3][0] += al.w * hf0; acc[3][1] += al.w * hf1;
        acc[3][2] += al.w * hf2; acc[3][3] += al.w * hf3;
      }
    }
    // reduce sum over 16 i16-lanes (per head group)
#pragma unroll
    for (int o = 1; o < 16; o <<= 1) sum += __shfl_xor(sum, o, 64);
    float inv = 1.f / sum;
    float ih4[4];
#pragma unroll
    for (int hh = 0; hh < 4; ++hh) ih4[hh] = __shfl(inv, hh * 16, 64);
    // reduce acc over 4 edge-groups (lane>>4): 2 levels
#pragma unroll
    for (int hh = 0; hh < 4; ++hh)
#pragma unroll
      for (int j = 0; j < 4; ++j) {
        acc[hh][j] += __shfl_xor(acc[hh][j], 16, 64);
        acc[hh][j] += __shfl_xor(acc[hh][j], 32, 64);
      }
    if (lane < 16) {
#pragma unroll
      for (int hh = 0; hh < 4; ++hh) {
        short4 o4;
        o4.x = f2bf(acc[hh][0] * ih4[hh]);
        o4.y = f2bf(acc[hh][1] * ih4[hh]);
        o4.z = f2bf(acc[hh][2] * ih4[hh]);
        o4.w = f2bf(acc[hh][3] * ih4[hh]);
        *(short4*)(agls + (w * 4 + i) * 264 + hh * 64 + i16 * 4) = o4;
      }
    }
  }
  __syncthreads();
  // MFMA update: A row = node q (agg, K=256), B = folded weights; out cols w*16..+16
  const short* arow = agls + q * 264;
  f32x4 z = {0.f, 0.f, 0.f, 0.f};
#pragma unroll
  for (int kh = 0; kh < 8; ++kh) {
    bf16x8 A = *(const bf16x8*)(arow + kh * 32 + g * 8);
    bf16x8 B = *(const bf16x8*)(updf + ((size_t)(w * 8 + kh) * 64 + lane) * 8);
    z = mfma16(A, B, z);
  }
  int c = w * 16 + q;
  float bf = 0.25f * (bl[c] + bl[64 + c] + bl[128 + c] + bl[192 + c]) + bias[c];
#pragma unroll
  for (int r = 0; r < 4; ++r) {
    int n = n0 + g * 4 + r;
    float nh = h[(size_t)n * 64 + c] + fmaxf(z[r] + bf, 0.f);
    h[(size_t)n * 64 + c] = nh;
    hbout[(size_t)n * 64 + c] = f2bf(nh);
  }
}

// ---------------- fused output heads ----------------
__global__ __launch_bounds__(256) void k_heads(
    const short* __restrict__ hb, const short* __restrict__ efc,
    const int* __restrict__ src, const int* __restrict__ dst,
    const int* __restrict__ pos, const short* __restrict__ eclsf,
    const float* __restrict__ b1, const float* __restrict__ w2,
    const float* __restrict__ b2,
    const float* __restrict__ h, const float* __restrict__ ow1,
    const float* __restrict__ ob1, const float* __restrict__ ow2,
    const float* __restrict__ ob2, float* __restrict__ out) {
  __shared__ __align__(16) char smraw[25600];
  int tid = threadIdx.x;
  int w = tid >> 6, lane = tid & 63, q = lane & 15, g = lane >> 4;
  if (blockIdx.x < ECLS_BLK) {
    short* smA = (short*)smraw;                  // 3 planes x 64 edges x 64 shorts = 24 KB
    float* sm = (float*)(smraw + 24576);         // 256 floats
    int e0b = blockIdx.x * 64;
    int id6[6];
#pragma unroll
    for (int j = 0; j < 6; ++j) {
      int s = (w * 6 + j) * 64 + lane;           // 0..1535
      int r = s >> 9, e = (s >> 3) & 63;
      int eg = e0b + e;
      id6[j] = (r == 0) ? src[eg] : (r == 1) ? dst[eg] : pos[eg];
    }
#pragma unroll
    for (int j = 0; j < 6; ++j) {
      int s = (w * 6 + j) * 64 + lane;
      int r = s >> 9, e = (s >> 3) & 63, c16 = s & 7;
      int cs = (c16 ^ (e & 7)) * 8;              // pre-swizzled short offset
      const short* gp = ((r == 2) ? efc : hb) + (size_t)id6[j] * 64 + cs;
      gl16(gp, &smA[(size_t)s * 8]);
    }
    int c = w * 16 + q;
    bf16x8 Bf[6];
#pragma unroll
    for (int kh = 0; kh < 6; ++kh)
      Bf[kh] = *(const bf16x8*)(eclsf + ((size_t)(w * 6 + kh) * 64 + lane) * 8);
    float b1v = b1[c], w2v = w2[c], b2v = b2[0];
    __syncthreads();  // drains staging vmcnt
    int xa = (g ^ (q & 7)) * 8;
    int xb = ((4 + g) ^ (q & 7)) * 8;
#pragma unroll
    for (int tile = 0; tile < 4; ++tile) {
      const short* rp = smA + (tile * 16 + q) * 64;
      f32x4 acc = {0.f, 0.f, 0.f, 0.f};
      acc = mfma16(*(const bf16x8*)(rp + xa), Bf[0], acc);
      acc = mfma16(*(const bf16x8*)(rp + xb), Bf[1], acc);
      acc = mfma16(*(const bf16x8*)(rp + 4096 + xa), Bf[2], acc);
      acc = mfma16(*(const bf16x8*)(rp + 4096 + xb), Bf[3], acc);
      acc = mfma16(*(const bf16x8*)(rp + 8192 + xa), Bf[4], acc);
      acc = mfma16(*(const bf16x8*)(rp + 8192 + xb), Bf[5], acc);
#pragma unroll
      for (int r = 0; r < 4; ++r) {
        float hv = fmaxf(acc[r] + b1v, 0.f) * w2v;
        hv += __shfl_xor(hv, 1, 64);
        hv += __shfl_xor(hv, 2, 64);
        hv += __shfl_xor(hv, 4, 64);
        hv += __shfl_xor(hv, 8, 64);
        if (q == 0) sm[tile * 64 + w * 16 + g * 4 + r] = hv;
      }
    }
    __syncthreads();
    if (tid < 64) {
      int tile = tid >> 4, e = tid & 15;
      float t = sm[tile * 64 + e] + sm[tile * 64 + 16 + e] +
                sm[tile * 64 + 32 + e] + sm[tile * 64 + 48 + e] + b2v;
      out[e0b + tile * 16 + e] = 1.f / (1.f + __expf(-t));
    }
  } else {
    // ---- offset regressor ----
    float* w1l = (float*)smraw;  // 4096 floats
#pragma unroll
    for (int qq = 0; qq < 16; ++qq) w1l[qq * 256 + tid] = ow1[qq * 256 + tid];
    __syncthreads();
    int n = (blockIdx.x - ECLS_BLK) * 4 + w;
    float hr = h[n * 64 + lane];
    float hid = ob1[lane];
#pragma unroll
    for (int k = 0; k < 64; ++k) hid += bcast(hr, k) * w1l[k * 64 + lane];
    hid = fmaxf(hid, 0.f);
    float p0 = wred_sum(hid * ow2[lane * 2]);
    float p1 = wred_sum(hid * ow2[lane * 2 + 1]);
    if (lane == 0) {
      out[N_EDGES + n * 2] = p0 + ob2[0];
      out[N_EDGES + n * 2 + 1] = p1 + ob2[1];
    }
  }
}

// ---------------- launcher ----------------

extern "C" void kernel_launch(void* const* d_in, const int* in_sizes, int n_in,
                              void* d_out, int out_size, void* d_ws, size_t ws_size,
                              hipStream_t stream) {
  const float* x     = (const float*)d_in[0];
  const int*   eidx  = (const int*)d_in[1];
  const float* eattr = (const float*)d_in[2];
  const float* ne_w1 = (const float*)d_in[3];
  const float* ne_b1 = (const float*)d_in[4];
  const float* ne_w2 = (const float*)d_in[5];
  const float* ne_b2 = (const float*)d_in[6];
  const float* ee_w1 = (const float*)d_in[7];
  const float* ee_b1 = (const float*)d_in[8];
  const float* ee_w2 = (const float*)d_in[9];
  const float* ee_b2 = (const float*)d_in[10];
  const float* cv_wl = (const float*)d_in[11];
  const float* cv_bl = (const float*)d_in[12];
  const float* cv_wr = (const float*)d_in[13];
  const float* cv_br = (const float*)d_in[14];
  const float* cv_we = (const float*)d_in[15];
  const float* cv_att = (const float*)d_in[16];
  const float* cv_bias = (const float*)d_in[17];
  const float* ec_w1 = (const float*)d_in[18];
  const float* ec_b1 = (const float*)d_in[19];
  const float* ec_w2 = (const float*)d_in[20];
  const float* ec_b2 = (const float*)d_in[21];
  const float* or_w1 = (const float*)d_in[22];
  const float* or_b1 = (const float*)d_in[23];
  const float* or_w2 = (const float*)d_in[24];
  const float* or_b2 = (const float*)d_in[25];

  const int* src = eidx;
  const int* dst = eidx + N_EDGES;

  // workspace layout
  float* fws = (float*)d_ws;
  size_t o = 0;
  float* h  = fws + o; o += (size_t)N_NODES * 64;
  float* lg = fws + o; o += (size_t)EP * 4;   // layout [p][4]
  short* sws = (short*)(fws + o);
  size_t so = 0;
  short* hb0  = sws + so; so += (size_t)N_NODES * 64;
  short* hb1  = sws + so; so += (size_t)N_NODES * 64;
  short* efc  = sws + so; so += (size_t)EP * 64;
  short* wlf  = sws + so; so += 3 * PREP_SEG;
  short* wrf  = sws + so; so += 3 * PREP_SEG;
  short* wef  = sws + so; so += 3 * PREP_SEG;
  short* updf = sws + so; so += 3 * PREP_SEG;
  short* eclsf = sws + so; so += 12288;
  short* encf  = sws + so; so += 4096;
  int* iws = (int*)(sws + so + (so & 1));
  int* row_ptr = iws;
  int* col_idx = iws + (N_NODES + 64);
  int* pdst = col_idx + EP;
  int* psrc = pdst + EP;
  int* pos  = psrc + EP;
  int* cnt  = pos + EP;
  int* fill = cnt + N_NODES;
  int* bsum = fill + N_NODES;

  float* out = (float*)d_out;

  // weight fragment prep + cnt/fill zeroing
  k_prep_all<<<(12 * PREP_SEG + 12288 + 4096 + 2 * N_NODES + 255) / 256, 256, 0, stream>>>(
      cv_wl, cv_wr, cv_we, ec_w1, ee_w2, wlf, wrf, wef, updf, eclsf, encf, cnt, fill);

  // CSR build
  k_count<<<(N_EDGES + 255) / 256, 256, 0, stream>>>(dst, cnt);
  k_scan1<<<NBLK, 256, 0, stream>>>(cnt, row_ptr, bsum);
  k_scan23<<<1, 256, 0, stream>>>(bsum, row_ptr);
  k_scatter<<<(EP + 255) / 256, 256, 0, stream>>>(dst, row_ptr, fill, col_idx, pdst);
  k_sortp<<<(N_NODES + 255) / 256, 256, 0, stream>>>(row_ptr, col_idx, src, psrc, pos);

  // encoders (edge blocks + node blocks fused)
  k_enc<<<EENC_BLK + N_NODES / 4, 256, 0, stream>>>(
      x, ne_w1, ne_b1, ne_w2, ne_b2, eattr, ee_w1, ee_b1, encf, ee_b2, pos, efc, h, hb0);
  k_loop_feat<<<N_NODES / 4, 256, 0, stream>>>(row_ptr, efc);

  // 3 GATv2 layers (hb ping-pong)
  short* hcur = hb0;
  short* hnxt = hb1;
  for (int l = 0; l < 3; ++l) {
    const float* bl = cv_bl + (size_t)l * 256;
    const float* br = cv_br + (size_t)l * 256;
    const float* at = cv_att + (size_t)l * 256;
    const float* bi = cv_bias + (size_t)l * 64;
    k_elog<<<(EP + 127) / 128, 256, 0, stream>>>(hcur, efc, psrc, pdst,
                                                 wlf + (size_t)l * PREP_SEG,
                                                 wrf + (size_t)l * PREP_SEG,
                                                 wef + (size_t)l * PREP_SEG, bl, br, at, lg);
    k_aggupd<<<N_NODES / 16, 256, 0, stream>>>(hcur, lg, row_ptr, psrc,
                                               updf + (size_t)l * PREP_SEG, bl, bi, h, hnxt);
    short* tmp = hcur; hcur = hnxt; hnxt = tmp;
  }

  // fused heads (final hb = hcur)
  k_heads<<<ECLS_BLK + N_NODES / 4, 256, 0, stream>>>(
      hcur, efc, src, dst, pos, eclsf, ec_b1, ec_w2, ec_b2,
      h, or_w1, or_b1, or_w2, or_b2, out);
}